// Round 5
// baseline (1077.825 us; speedup 1.0000x reference)
//
#include <hip/hip_runtime.h>
#include <hip/hip_bf16.h>
#include <stdint.h>

// SymmetricHyperRBM on MI355X. K=10 Gibbs chain + free-energy gap.
// fp8 e4m3; FiLM biases folded into GEMM K-dim; XCD swizzle; inline-u chain.
// R18: counted-vmcnt two-barrier K-loop (T4): per iter {issue prefetch ->
// s_waitcnt vmcnt(4|3) [waits only LAST iter's staging; fresh prefetch stays
// in flight] -> s_barrier -> compute -> s_barrier}. Replaces __syncthreads'
// unconditional vmcnt(0) drain, which serialized every K-iter on the staging
// round trip (R17 chain budget: ~45% stall, LDS 24%, MFMA 10%).
// Two-barrier discipline: bar1 after each wave's own counted wait certifies
// cross-wave staging; bar2 orders reads-of-base before next overwrite.
// R17 carried: chain BM=128 (4 waves x 64x64, acc[4][4], grid 1024);
// EPI2 BM=64 + split-acc K=1152 (R16, cmod/k_bmod eliminated); stage-ahead
// prefetch double-buffer (R15); fast softplus; double-XOR chunk swizzle.

#define NB 16384
#define KSTEPS 10
#define LDA 1152           // bytes/row: 1024 state + 64 X + 1 const + 63 pad
#define SLS 136            // epilogue slab row stride in bytes (128 + 8 pad)
#define USALT 4000u
#define ONE8 ((unsigned char)0x38)  // fp8 e4m3 1.0

typedef __attribute__((ext_vector_type(4))) float f32x4;
typedef __attribute__((ext_vector_type(4))) unsigned int u32x4;

__device__ __forceinline__ unsigned hash32(unsigned idx, unsigned salt) {
  unsigned x = idx + salt * 0x9E3779B9u;
  x = (x ^ (x >> 16)) * 0x7feb352du;
  x = (x ^ (x >> 15)) * 0x846ca68bu;
  return x ^ (x >> 16);
}
__device__ __forceinline__ float rng_u01(unsigned salt, unsigned idx) {
  return (float)(hash32(idx, salt) >> 8) * (1.0f / 16777216.0f);
}
__device__ __forceinline__ float sigm(float z) { return 1.0f / (1.0f + __expf(-z)); }
// fast softplus: max(z,0) + log(1+exp(-|z|)); v_exp/v_log based (~7 ops vs
// ~25+branch for log1pf form). |err| ~1e-6, negligible vs fp8 quantization.
__device__ __forceinline__ float softplus_(float z) {
  return fmaxf(z, 0.f) + __logf(1.f + __expf(-fabsf(z)));
}
__device__ __forceinline__ float lse2(float a, float b) {
  float m = fmaxf(a, b);
  return m + log1pf(__expf(fminf(a, b) - m));
}
__device__ __forceinline__ float bf2f(unsigned short s) {
  unsigned u = ((unsigned)s) << 16;
  return *reinterpret_cast<float*>(&u);
}
__device__ __forceinline__ unsigned short f2bf(float f) {
  __hip_bfloat16 h = __float2bfloat16(f);
  return *reinterpret_cast<unsigned short*>(&h);
}
// float -> fp8 e4m3fn (OCP), RNE, saturating. Setup-path only.
__device__ unsigned char f2e4m3(float f) {
  unsigned u = __float_as_uint(f);
  unsigned char s = (unsigned char)((u >> 24) & 0x80);
  float af = fabsf(f);
  if (af >= 448.f) return s | 0x7E;
  float sub = rintf(af * 512.f);
  if (sub < 1.f) return s;                 // underflow -> 0
  if (af < 0.015625f) {                    // subnormal, step 2^-9
    int m = (int)sub;
    if (m > 7) return s | 0x08;
    return s | (unsigned char)m;
  }
  int ex; frexpf(af, &ex);
  int E = ex - 1;                          // af in [2^E, 2^(E+1))
  float q = rintf(ldexpf(af, 3 - E));      // in [8,16]
  int qi = (int)q;
  if (qi >= 16) { qi = 8; E += 1; if (E > 8) return s | 0x7E; }
  return s | (unsigned char)(((E + 7) << 3) | (qi - 8));
}
__device__ __forceinline__ void gl2lds16(const void* g, void* l) {
  __builtin_amdgcn_global_load_lds(
      (const __attribute__((address_space(1))) unsigned int*)g,
      (__attribute__((address_space(3))) unsigned int*)l, 16, 0, 0);
}

// ---------------------------------------------------------------------------
// C = A[16384 x Kdim] * Bt[. x Kdim]^T, fp8 MFMA 16x16x32, BK=64,
// double-buffered LDS, counted-vmcnt two-barrier pipeline (R18).
// Chain (EPI0/1): BM=128 tile, 4 waves x 64x64, grid 1024:
//   xcd=L&7, li=L>>3; m0 = xcd*2048 + (li&15)*128; n-tile = li>>4.
// EPI2: BM=64 tile, 4 waves x 32x64, grid 2304 (incl. bias n-tile 8):
//   m0 = xcd*2048 + (li&31)*64; n-tile = li>>5.
// EPI 0: h = bern(sigm(z1)) -> sh (pure sampler).
// EPI 1: u_t inline from (pv0,pv1,usalt); p0+=sum z, p1+=sum v*z
//        (v = u_t ? s_old : 1-s_old, scattered L2 reads); s_new -> sh.
// EPI 2: K=1152 split-acc (acc: k<1024 = vW; accf: k>=1024 = c_mod).
//        n<8: softplus rows -> p0,p1; n==8: bias-dots (acc . X -> p2).
// ---------------------------------------------------------------------------
template <int EPI>
__global__ __launch_bounds__(256, 4) void gemm_bt(
    const unsigned char* __restrict__ A, const unsigned char* __restrict__ Bt,
    unsigned char* sh, const unsigned short* __restrict__ mod,
    const float* __restrict__ wcs, const float* __restrict__ Xf,
    const float* __restrict__ pv0, const float* __restrict__ pv1, unsigned usalt,
    float* __restrict__ p0, float* __restrict__ p1, float* __restrict__ p2,
    unsigned salt, int Kdim) {
  constexpr int MI = (EPI == 2 ? 2 : 4);   // 16-row tiles per wave (M dir)
  constexpr int BM = MI * 32;              // block rows: 64 (EPI2) / 128
  constexpr int ABYT = BM * 64;            // A-panel bytes/buffer: 4K / 8K
  constexpr int BUF = ABYT + 8192;         // buffer stride: 12K / 16K
  // epilogue slab BM x 136 B aliases the front after the loop (chain only)
  __shared__ __align__(16) char smem[2 * BUF];
  unsigned char* newsl = (unsigned char*)smem;

  const int t = threadIdx.x;
  const int L = blockIdx.x;
  const int xcd = L & 7, li = L >> 3;
  constexpr int MMSK = (EPI == 2 ? 31 : 15);
  constexpr int NSH = (EPI == 2 ? 5 : 4);
  const int m0 = xcd * 2048 + (li & MMSK) * BM;
  const int n0 = (li >> NSH) * 128;
  const int lane = t & 63, wave = t >> 6;
  const int wm = (wave >> 1) * (MI * 16), wn = (wave & 1) * 64;
  const int lr = lane & 15, quad = lane >> 4;
  // staging: lane -> row = lane>>2, phys chunk lane&3; gathers LOGICAL chunk
  // q = (lane&3) ^ (row&3) ^ ((lane>>4)&3)   [double-XOR swizzle]
  const int row8 = lane >> 2;
  const int qch = (((lane & 3) ^ (row8 & 3) ^ ((lane >> 4) & 3)) << 4);
  // fragment read offsets: phys chunk = (s*2+qh) ^ (lr&3) ^ ((lr>>2)&3)
  const int ql8 = (quad & 1) * 8, qh = quad >> 1;
  const int rx = (lr & 3) ^ ((lr >> 2) & 3);
  int koff[2];
#pragma unroll
  for (int s = 0; s < 2; ++s) koff[s] = (((s * 2 + qh) ^ rx) << 4) + ql8;

  // hoisted staging pointers (advance 64 B per K-iter)
  const unsigned char* gA0 = A + (size_t)(m0 + wave * (MI * 8) + row8) * LDA + qch;
  const unsigned char* gA1 = gA0 + (size_t)16 * LDA;  // chain only
  const unsigned char* gB0 = Bt + (size_t)(n0 + wave * 32 + row8) * LDA + qch;
  const unsigned char* gB1 = gB0 + (size_t)16 * LDA;

  auto stage = [&](int bufb) {
    if constexpr (EPI == 2) {
      gl2lds16(gA0, smem + bufb + wave * 1024);
    } else {
      gl2lds16(gA0, smem + bufb + wave * 2048);
      gl2lds16(gA1, smem + bufb + wave * 2048 + 1024);
      gA1 += 64;
    }
    gl2lds16(gB0, smem + bufb + ABYT + wave * 2048);
    gl2lds16(gB1, smem + bufb + ABYT + wave * 2048 + 1024);
    gA0 += 64; gB0 += 64; gB1 += 64;
  };

  f32x4 acc[MI][4] = {};
  f32x4 accf[EPI == 2 ? MI : 1][4] = {};  // EPI2 only: FiLM (k>=1024) = c_mod
  const int nt = Kdim >> 6;

  // prologue: stage K-tile 0 into buffer 0; NO drain — iter 0's counted
  // wait (vmcnt(PF)) covers it after issuing the iter-0 prefetch.
  stage(0);

  int base = 0;
  for (int it = 0; it < nt; ++it) {
    const int nb = base ^ BUF;
    if (it + 1 < nt) {
      stage(nb);  // prefetch next K-tile; stays in flight across barrier
      // wait only the PREVIOUS staging (3 loads/wave EPI2, 4 chain);
      // the fresh prefetch's loads remain outstanding (T4 counted vmcnt).
      if constexpr (EPI == 2) asm volatile("s_waitcnt vmcnt(3)" ::: "memory");
      else                    asm volatile("s_waitcnt vmcnt(4)" ::: "memory");
    } else {
      asm volatile("s_waitcnt vmcnt(0)" ::: "memory");  // tail: drain all
    }
    // bar1: every wave certified its OWN prior staging landed -> cross-wave
    // LDS sections of `base` are valid for all readers.
    asm volatile("s_barrier" ::: "memory");
    const char* sA = (const char*)smem + base;
    const char* sB = sA + ABYT;
#pragma unroll
    for (int s = 0; s < 2; ++s) {  // two K=32 slices of the 64-B row
      long af[MI], bfr[4];
#pragma unroll
      for (int i = 0; i < MI; i++)
        af[i] = *(const long*)(sA + (wm + i * 16 + lr) * 64 + koff[s]);
#pragma unroll
      for (int j = 0; j < 4; j++)
        bfr[j] = *(const long*)(sB + (wn + j * 16 + lr) * 64 + koff[s]);
      if (EPI == 2 && it >= 16) {  // FiLM columns -> accf (uniform branch)
#pragma unroll
        for (int i = 0; i < MI; i++)
#pragma unroll
          for (int j = 0; j < 4; j++)
            accf[i][j] = __builtin_amdgcn_mfma_f32_16x16x32_fp8_fp8(af[i], bfr[j], accf[i][j], 0, 0, 0);
      } else {
#pragma unroll
        for (int i = 0; i < MI; i++)
#pragma unroll
          for (int j = 0; j < 4; j++)
            acc[i][j] = __builtin_amdgcn_mfma_f32_16x16x32_fp8_fp8(af[i], bfr[j], acc[i][j], 0, 0, 0);
      }
    }
    // bar2: all reads of `base` retired (compiler's lgkmcnt precedes the
    // consuming MFMAs, which precede this barrier) -> next iteration's
    // prefetch may overwrite it.
    asm volatile("s_barrier" ::: "memory");
    base = nb;
  }

  // C/D layout (m89, dtype-independent): col = lane&15, row = quad*4 + reg
  if constexpr (EPI == 2) {
    if (n0 >= 1024) {  // bias-dot tile: cols 1024..1088 = [Gb-dots | cstb]
#pragma unroll
      for (int i = 0; i < MI; i++)
#pragma unroll
        for (int rg = 0; rg < 4; rg++) {
          const int r = m0 + wm + i * 16 + quad * 4 + rg;
          float pb = 0.f;
          if (wn == 0) {  // cg = j*16+lr in 0..63: G-dots with X[r]
#pragma unroll
            for (int j = 0; j < 4; j++)
              pb += acc[i][j][rg] * Xf[(size_t)r * 64 + j * 16 + lr];
          } else {        // col 1088 (j==0,lr==0): cst-dot
            if (lr == 0) pb = acc[i][0][rg];
          }
#pragma unroll
          for (int msk = 1; msk < 16; msk <<= 1) pb += __shfl_xor(pb, msk, 64);
          if (lr == 0) atomicAdd(&p2[r], pb);
        }
      return;
    }
#pragma unroll
    for (int i = 0; i < MI; i++)
#pragma unroll
      for (int rg = 0; rg < 4; rg++) {
        const int r = m0 + wm + i * 16 + quad * 4 + rg;
        bool uu = true;
        if (pv0 != nullptr) {
          const float dE = -pv0[r] + 2.f * pv1[r];
          uu = rng_u01(usalt, (unsigned)r) < sigm(dE);
        }
        float sn = 0.f, sf = 0.f;
#pragma unroll
        for (int j = 0; j < 4; j++) {
          const int n = n0 + wn + j * 16 + lr;
          const float vw = acc[i][j][rg];
          const float cm = accf[i][j][rg];  // c_mod from FiLM K-columns
          const float s1 = softplus_(vw + cm);
          const float s2 = softplus_(wcs[n] - vw + cm);
          sn += uu ? s1 : s2;
          sf += uu ? s2 : s1;
        }
#pragma unroll
        for (int msk = 1; msk < 16; msk <<= 1) {
          sn += __shfl_xor(sn, msk, 64);
          sf += __shfl_xor(sf, msk, 64);
        }
        if (lr == 0) { atomicAdd(&p0[r], sn); atomicAdd(&p1[r], sf); }
      }
    return;
  }

  if constexpr (EPI == 1) {  // z-sums with v from OLD s; u_t inline
#pragma unroll
    for (int i = 0; i < MI; i++)
#pragma unroll
      for (int rg = 0; rg < 4; rg++) {
        const int r = m0 + wm + i * 16 + quad * 4 + rg;
        const float dE = -pv0[r] + 2.f * pv1[r];
        const bool uu = rng_u01(usalt, (unsigned)r) < sigm(dE);
        float q0 = 0.f, q1 = 0.f;
#pragma unroll
        for (int j = 0; j < 4; ++j) {
          const float z = acc[i][j][rg];
          const float so = (sh[(size_t)r * LDA + n0 + wn + j * 16 + lr] != 0) ? 1.f : 0.f;
          const float v = uu ? so : 1.f - so;
          q0 += z; q1 += v * z;
        }
#pragma unroll
        for (int msk = 1; msk < 16; msk <<= 1) {
          q0 += __shfl_xor(q0, msk, 64);
          q1 += __shfl_xor(q1, msk, 64);
        }
        if (lr == 0) { atomicAdd(&p0[r], q0); atomicAdd(&p1[r], q1); }
      }
  }

  // EPI 0/1: sample into BM-row slab, 1 barrier, coalesced store
#pragma unroll
  for (int i = 0; i < MI; ++i)
#pragma unroll
    for (int rg = 0; rg < 4; ++rg) {
      const int rowl = wm + i * 16 + quad * 4 + rg;  // 0..BM-1 in tile
      const int r = m0 + rowl;
#pragma unroll
      for (int jp = 0; jp < 2; ++jp) {
        const unsigned x = hash32((unsigned)(r << 10) + (unsigned)(n0 + wn + jp * 16 + lr), salt);
        const float f0 = (float)(x & 0xFFFFu), f1 = (float)(x >> 16);
        const float z0 = acc[i][jp][rg], z1v = acc[i][jp + 2][rg];
        newsl[rowl * SLS + wn + jp * 16 + lr] =
            (f0 * __expf(-z0) < 65536.f - f0) ? ONE8 : (unsigned char)0;
        newsl[rowl * SLS + wn + (jp + 2) * 16 + lr] =
            (f1 * __expf(-z1v) < 65536.f - f1) ? ONE8 : (unsigned char)0;
      }
    }
  __syncthreads();
#pragma unroll
  for (int p = 0; p < BM / 32; ++p) {  // BM rows x 128 B, fully coalesced
    const int c = p * 256 + t, rowl = c >> 3, chk = c & 7;
    const u32x4 vv = *(const u32x4*)(newsl + rowl * SLS + chk * 16);
    *(u32x4*)(sh + (size_t)(m0 + rowl) * LDA + n0 + chk * 16) = vv;
  }
}

// ------------------------- setup / small kernels ---------------------------
__global__ __launch_bounds__(256) void k_x(const float* __restrict__ cond,
                                           const float* __restrict__ fc1w,
                                           const float* __restrict__ fc1b, float* __restrict__ X) {
  int idx = blockIdx.x * 256 + threadIdx.x;
  int r = idx >> 6, k = idx & 63;
  X[idx] = tanhf(cond[r] * fc1w[k] + fc1b[k]);
}

__global__ __launch_bounds__(256) void k_g(const float* __restrict__ fc2w,
                                           const float* __restrict__ fc2b,
                                           const float* __restrict__ b, const float* __restrict__ c,
                                           float* __restrict__ Gb, float* __restrict__ Gc,
                                           float* __restrict__ cstb, float* __restrict__ cstc) {
  int idx = blockIdx.x * 256 + threadIdx.x;
  int j = idx >> 6, k = idx & 63;
  Gb[idx] = fc2w[(size_t)j * 64 + k] * b[j] + fc2w[(size_t)(1024 + j) * 64 + k];
  Gc[idx] = fc2w[(size_t)(2048 + j) * 64 + k] * c[j] + fc2w[(size_t)(3072 + j) * 64 + k];
  if (k == 0) {
    cstb[j] = b[j] + fc2b[j] * b[j] + fc2b[1024 + j];
    cstc[j] = c[j] + fc2b[2048 + j] * c[j] + fc2b[3072 + j];
  }
}

// Wt rows n<1024: [W^T|Gc|cstc|pad]; rows 1024..1088: [Gb-col profiles|cstb]
// (those rows are zero at k>=1024, so EPI2's accf==0 on the bias-dot tile).
// Wb rows n<1024: [W|Gb|cstb|pad]; rows beyond unused for Wb.
__global__ __launch_bounds__(256) void k_prep(const float* __restrict__ W,
                                              const float* __restrict__ Gb,
                                              const float* __restrict__ Gc,
                                              const float* __restrict__ cstb,
                                              const float* __restrict__ cstc,
                                              unsigned char* __restrict__ Wt,
                                              unsigned char* __restrict__ Wb) {
  int k = blockIdx.x * 256 + threadIdx.x;
  int n = blockIdx.y;
  if (k >= LDA) return;
  unsigned char wt = 0, wb = 0;
  if (n < 1024) {
    if (k < 1024) {
      wt = f2e4m3(W[(size_t)k * 1024 + n]);
      wb = f2e4m3(W[(size_t)n * 1024 + k]);
    } else if (k < 1088) {
      int j = k - 1024;
      wt = f2e4m3(Gc[(size_t)n * 64 + j]);
      wb = f2e4m3(Gb[(size_t)n * 64 + j]);
    } else if (k == 1088) {
      wt = f2e4m3(cstc[n]);
      wb = f2e4m3(cstb[n]);
    }
  } else if (k < 1024) {
    if (n < 1088) wt = f2e4m3(Gb[(size_t)k * 64 + (n - 1024)]);
    else if (n == 1088) wt = f2e4m3(cstb[k]);
  }
  Wt[(size_t)n * LDA + k] = wt;
  Wb[(size_t)n * LDA + k] = wb;
}

__global__ __launch_bounds__(256) void k_wcs(const float* __restrict__ W, float* __restrict__ wcs) {
  int n = blockIdx.x * 256 + threadIdx.x;
  float s = 0.f;
  for (int i = 0; i < 1024; i++) s += W[(size_t)i * 1024 + n];
  wcs[n] = s;
}

// aux[k<64] = sum_j Gb[j][k]; aux[64] = sum_j cstb[j]
__global__ __launch_bounds__(128) void k_aux(const float* __restrict__ Gb,
                                             const float* __restrict__ cstb,
                                             float* __restrict__ aux) {
  int t = threadIdx.x;
  if (t < 64) {
    float s = 0.f;
    for (int j = 0; j < 1024; j++) s += Gb[(size_t)j * 64 + t];
    aux[t] = s;
  } else if (t == 64) {
    float s = 0.f;
    for (int j = 0; j < 1024; j++) s += cstb[j];
    aux[64] = s;
  }
}

__global__ __launch_bounds__(256) void k_sinit(const float* __restrict__ vdata,
                                               const float* __restrict__ X,
                                               unsigned char* __restrict__ S,
                                               unsigned char* __restrict__ H,
                                               unsigned char* __restrict__ V) {
  int k = blockIdx.x * 256 + threadIdx.x;
  int r = blockIdx.y;
  if (k >= LDA) return;
  const size_t o = (size_t)r * LDA + k;
  if (k < 1024) {
    float vd = vdata[(size_t)r * 1024 + k];
    V[o] = (vd != 0.f) ? ONE8 : (unsigned char)0;
    const bool u0 = rng_u01(USALT, (unsigned)r) < 0.5f;  // == EPI1 step-0 formula
    float sv = u0 ? vd : 1.f - vd;
    S[o] = (sv != 0.f) ? ONE8 : (unsigned char)0;
  } else {
    unsigned char xv;
    if (k < 1088) xv = f2e4m3(X[(size_t)r * 64 + (k - 1024)]);
    else if (k == 1088) xv = ONE8;  // 1.0
    else xv = 0;
    S[o] = xv; H[o] = xv; V[o] = xv;  // V needs FiLM cols for EPI2 K=1152
  }
}

// per-row scalar finale: sb from rank-64 closed form, d1/d2 from bias-dots
__global__ __launch_bounds__(256) void k_final(
    const float* __restrict__ Xf, const float* __restrict__ aux,
    const float* __restrict__ pv0, const float* __restrict__ pv1, unsigned usalt,
    const float* __restrict__ spn_d, const float* __restrict__ spf_d,
    const float* __restrict__ spn_m, const float* __restrict__ spf_m,
    const float* __restrict__ vb_d, const float* __restrict__ vb_m,
    float* __restrict__ fdiff) {
  __shared__ float ax[65];
  int t = threadIdx.x;
  if (t < 65) ax[t] = aux[t];
  __syncthreads();
  int r = blockIdx.x * 256 + t;
  float sb = ax[64];
  const float* xr = Xf + (size_t)r * 64;
#pragma unroll
  for (int k = 0; k < 64; k++) sb += xr[k] * ax[k];
  const float dE = -pv0[r] + 2.f * pv1[r];
  const bool uu = rng_u01(usalt, (unsigned)r) < sigm(dE);
  const float d1 = vb_d[r], d2 = vb_m[r];
  float F_d = -lse2(d1 + spn_d[r], (sb - d1) + spf_d[r]);
  float vbn = uu ? d2 : (sb - d2);
  float F_m = -lse2(vbn + spn_m[r], (sb - vbn) + spf_m[r]);
  fdiff[r] = F_d - F_m;
}

__global__ __launch_bounds__(256) void k_reduce(const float* __restrict__ fdiff,
                                                float* __restrict__ out) {
  __shared__ float red[4];
  int t = threadIdx.x;
  float s = 0.f;
  for (int i = t; i < NB; i += 256) s += fdiff[i];
  for (int m = 32; m >= 1; m >>= 1) s += __shfl_xor(s, m, 64);
  if ((t & 63) == 0) red[t >> 6] = s;
  __syncthreads();
  if (t == 0) out[0] = (red[0] + red[1] + red[2] + red[3]) * (1.0f / (float)NB);
}

// ---------------------------------------------------------------------------
extern "C" void kernel_launch(void* const* d_in, const int* in_sizes, int n_in, void* d_out,
                              int out_size, void* d_ws, size_t ws_size, hipStream_t stream) {
  const float* vdata = (const float*)d_in[0];
  const float* cond = (const float*)d_in[1];
  const float* W = (const float*)d_in[2];
  const float* bb = (const float*)d_in[3];
  const float* cc = (const float*)d_in[4];
  const float* fc1w = (const float*)d_in[5];
  const float* fc1b = (const float*)d_in[6];
  const float* fc2w = (const float*)d_in[7];
  const float* fc2b = (const float*)d_in[8];
  float* out = (float*)d_out;

  char* wp = (char*)d_ws;
  auto alloc = [&](size_t bytes) {
    char* p = wp;
    wp += (bytes + 255) & ~(size_t)255;
    return p;
  };
  unsigned char* Wt = (unsigned char*)alloc((size_t)1152 * LDA);
  unsigned char* Wb = (unsigned char*)alloc((size_t)1152 * LDA);
  float* wcs = (float*)alloc(1024 * 4);
  float* X = (float*)alloc((size_t)NB * 64 * 4);
  float* Gb = (float*)alloc((size_t)1024 * 64 * 4);
  float* Gc = (float*)alloc((size_t)1024 * 64 * 4);
  float* cstb = (float*)alloc(1024 * 4);
  float* cstc = (float*)alloc(1024 * 4);
  float* aux = (float*)alloc(65 * 4);
  unsigned char* S = (unsigned char*)alloc((size_t)NB * LDA);
  unsigned char* H = (unsigned char*)alloc((size_t)NB * LDA);
  unsigned char* V = (unsigned char*)alloc((size_t)NB * LDA);
  // per-step dE accumulators: pair t at pall + (t+1)*2*NB, t=-1..9; then 6 arrays
  float* pall = (float*)alloc((size_t)(KSTEPS + 1 + 3) * 2 * NB * 4);
  float* spn_d = pall + (size_t)(KSTEPS + 1) * 2 * NB;
  float* spf_d = spn_d + NB;
  float* spn_m = spf_d + NB;
  float* spf_m = spn_m + NB;
  float* vb_d = spf_m + NB;
  float* vb_m = vb_d + NB;
  float* fdiff = (float*)alloc(NB * 4);
  auto P0 = [&](int t) { return pall + (size_t)(t + 1) * 2 * NB; };
  auto P1 = [&](int t) { return pall + (size_t)(t + 1) * 2 * NB + NB; };

  hipMemsetAsync(pall, 0, (size_t)(KSTEPS + 1 + 3) * 2 * NB * 4, stream);

  k_x<<<NB * 64 / 256, 256, 0, stream>>>(cond, fc1w, fc1b, X);
  k_g<<<1024 * 64 / 256, 256, 0, stream>>>(fc2w, fc2b, bb, cc, Gb, Gc, cstb, cstc);
  k_prep<<<dim3(5, 1152), 256, 0, stream>>>(W, Gb, Gc, cstb, cstc, Wt, Wb);
  k_wcs<<<4, 256, 0, stream>>>(W, wcs);
  k_aux<<<1, 128, 0, stream>>>(Gb, cstb, aux);
  k_sinit<<<dim3(5, NB), 256, 0, stream>>>(vdata, X, S, H, V);

  for (int step = 0; step < KSTEPS; ++step) {
    // z1 = sW + c_mod (ext-K); h ~ Bern(sigm(z1)) -> H
    gemm_bt<0><<<1024, 256, 0, stream>>>(S, Wt, H, nullptr, nullptr, nullptr,
                                         nullptr, nullptr, 0u, nullptr, nullptr, nullptr,
                                         2000u + (unsigned)step, LDA);
    // z2 = hW^T + b_mod (ext-K); u_t inline; dE partials -> step t; s_new -> S
    gemm_bt<1><<<1024, 256, 0, stream>>>(H, Wb, S, nullptr, nullptr, nullptr,
                                         P0(step - 1), P1(step - 1), USALT + (unsigned)step,
                                         P0(step), P1(step), nullptr,
                                         3000u + (unsigned)step, LDA);
  }

  // Free-energy: softplus rows (n-tiles 0..7, split-acc K=1152) +
  // bias-dots (n-tile 8). cmod table eliminated (R16).
  gemm_bt<2><<<2304, 256, 0, stream>>>(V, Wt, nullptr, nullptr, wcs, X, nullptr, nullptr, 0u,
                                       spn_d, spf_d, vb_d, 0u, LDA);
  gemm_bt<2><<<2304, 256, 0, stream>>>(S, Wt, nullptr, nullptr, wcs, X,
                                       P0(KSTEPS - 1), P1(KSTEPS - 1), USALT + KSTEPS,
                                       spn_m, spf_m, vb_m, 0u, LDA);
  k_final<<<NB / 256, 256, 0, stream>>>(X, aux, P0(KSTEPS - 1), P1(KSTEPS - 1), USALT + KSTEPS,
                                        spn_d, spf_d, spn_m, spf_m, vb_d, vb_m, fdiff);
  k_reduce<<<1, 256, 0, stream>>>(fdiff, out);
}

// Round 6
// 1040.436 us; speedup vs baseline: 1.0359x; 1.0359x over previous
//
#include <hip/hip_runtime.h>
#include <hip/hip_bf16.h>
#include <stdint.h>

// SymmetricHyperRBM on MI355X. K=10 Gibbs chain + free-energy gap.
// fp8 e4m3; FiLM biases folded into GEMM K-dim; XCD swizzle; inline-u chain.
// R19: (a) revert R18's two-barrier counted-vmcnt to the R17 single
// __syncthreads loop (R18 was neutral-to-negative: prefetch already lands
// within the compute phase; extra barrier = extra convergence). (b) K-dim
// 1152 -> 1088 (17 iters exact): the cst column (k=1088, only non-zero col
// of iter 17) moves to the epilogue as +cst8[n], where cst8 is the
// fp8-roundtripped constant (matches the old GEMM contribution). Removes
// 5.5% of main-loop work (stage+LDS+MFMA+barrier) from all 22 dispatches;
// 63 zero pad columns no longer multiplied.
// R17 carried: chain BM=128 (4 waves x 64x64, acc[4][4], grid 1024);
// EPI2 BM=64 + split-acc (R16, cmod/k_bmod eliminated; FiLM iter = it 16);
// stage-ahead prefetch double-buffer (R15); fast softplus; double-XOR
// chunk swizzle.

#define NB 16384
#define KSTEPS 10
#define LDA 1152           // bytes/row: 1024 state + 64 X + 1 const + 63 pad
#define KD 1088            // GEMM K-dim: 1024 state + 64 X (cst in epilogue)
#define SLS 136            // epilogue slab row stride in bytes (128 + 8 pad)
#define USALT 4000u
#define ONE8 ((unsigned char)0x38)  // fp8 e4m3 1.0

typedef __attribute__((ext_vector_type(4))) float f32x4;
typedef __attribute__((ext_vector_type(4))) unsigned int u32x4;

__device__ __forceinline__ unsigned hash32(unsigned idx, unsigned salt) {
  unsigned x = idx + salt * 0x9E3779B9u;
  x = (x ^ (x >> 16)) * 0x7feb352du;
  x = (x ^ (x >> 15)) * 0x846ca68bu;
  return x ^ (x >> 16);
}
__device__ __forceinline__ float rng_u01(unsigned salt, unsigned idx) {
  return (float)(hash32(idx, salt) >> 8) * (1.0f / 16777216.0f);
}
__device__ __forceinline__ float sigm(float z) { return 1.0f / (1.0f + __expf(-z)); }
// fast softplus: max(z,0) + log(1+exp(-|z|)); v_exp/v_log based (~7 ops vs
// ~25+branch for log1pf form). |err| ~1e-6, negligible vs fp8 quantization.
__device__ __forceinline__ float softplus_(float z) {
  return fmaxf(z, 0.f) + __logf(1.f + __expf(-fabsf(z)));
}
__device__ __forceinline__ float lse2(float a, float b) {
  float m = fmaxf(a, b);
  return m + log1pf(__expf(fminf(a, b) - m));
}
__device__ __forceinline__ float bf2f(unsigned short s) {
  unsigned u = ((unsigned)s) << 16;
  return *reinterpret_cast<float*>(&u);
}
__device__ __forceinline__ unsigned short f2bf(float f) {
  __hip_bfloat16 h = __float2bfloat16(f);
  return *reinterpret_cast<unsigned short*>(&h);
}
// float -> fp8 e4m3fn (OCP), RNE, saturating. Setup-path only.
__device__ unsigned char f2e4m3(float f) {
  unsigned u = __float_as_uint(f);
  unsigned char s = (unsigned char)((u >> 24) & 0x80);
  float af = fabsf(f);
  if (af >= 448.f) return s | 0x7E;
  float sub = rintf(af * 512.f);
  if (sub < 1.f) return s;                 // underflow -> 0
  if (af < 0.015625f) {                    // subnormal, step 2^-9
    int m = (int)sub;
    if (m > 7) return s | 0x08;
    return s | (unsigned char)m;
  }
  int ex; frexpf(af, &ex);
  int E = ex - 1;                          // af in [2^E, 2^(E+1))
  float q = rintf(ldexpf(af, 3 - E));      // in [8,16]
  int qi = (int)q;
  if (qi >= 16) { qi = 8; E += 1; if (E > 8) return s | 0x7E; }
  return s | (unsigned char)(((E + 7) << 3) | (qi - 8));
}
// e4m3fn -> float (for the epilogue cst: value == what the GEMM would add)
__device__ __forceinline__ float e4m3f(unsigned char v) {
  float s = (v & 0x80) ? -1.f : 1.f;
  int e = (v >> 3) & 15, m = v & 7;
  float mag = e ? ldexpf((float)(8 + m), e - 10) : ldexpf((float)m, -9);
  return s * mag;
}
__device__ __forceinline__ void gl2lds16(const void* g, void* l) {
  __builtin_amdgcn_global_load_lds(
      (const __attribute__((address_space(1))) unsigned int*)g,
      (__attribute__((address_space(3))) unsigned int*)l, 16, 0, 0);
}

// ---------------------------------------------------------------------------
// C = A[16384 x KD] * Bt[. x KD]^T (+cst8[n] in epilogue), fp8 MFMA 16x16x32,
// BK=64, double-buffered LDS with stage-ahead prefetch, ONE barrier/iter.
// Chain (EPI0/1): BM=128 tile, 4 waves x 64x64, grid 1024:
//   xcd=L&7, li=L>>3; m0 = xcd*2048 + (li&15)*128; n-tile = li>>4.
// EPI2: BM=64 tile, 4 waves x 32x64, grid 2304 (incl. bias n-tile 8):
//   m0 = xcd*2048 + (li&31)*64; n-tile = li>>5.
// EPI 0: h = bern(sigm(z1)) -> sh, z1 = acc + cstc8[n].
// EPI 1: u_t inline from (pv0,pv1,usalt); p0+=sum z, p1+=sum v*z,
//        z = acc + cstb8[n] (v = u_t ? s_old : 1-s_old); s_new -> sh.
// EPI 2: split-acc (acc: it<16 = vW; accf: it==16 = X.Gc); cm = accf+cstc8.
//        n<8: softplus rows -> p0,p1; n==8: bias-dots (acc . X -> p2).
// ---------------------------------------------------------------------------
template <int EPI>
__global__ __launch_bounds__(256, 4) void gemm_bt(
    const unsigned char* __restrict__ A, const unsigned char* __restrict__ Bt,
    unsigned char* sh, const float* __restrict__ cst8,
    const float* __restrict__ wcs, const float* __restrict__ Xf,
    const float* __restrict__ pv0, const float* __restrict__ pv1, unsigned usalt,
    float* __restrict__ p0, float* __restrict__ p1, float* __restrict__ p2,
    unsigned salt, int Kdim) {
  constexpr int MI = (EPI == 2 ? 2 : 4);   // 16-row tiles per wave (M dir)
  constexpr int BM = MI * 32;              // block rows: 64 (EPI2) / 128
  constexpr int ABYT = BM * 64;            // A-panel bytes/buffer: 4K / 8K
  constexpr int BUF = ABYT + 8192;         // buffer stride: 12K / 16K
  // epilogue slab BM x 136 B aliases the front after the loop (chain only)
  __shared__ __align__(16) char smem[2 * BUF];
  unsigned char* newsl = (unsigned char*)smem;

  const int t = threadIdx.x;
  const int L = blockIdx.x;
  const int xcd = L & 7, li = L >> 3;
  constexpr int MMSK = (EPI == 2 ? 31 : 15);
  constexpr int NSH = (EPI == 2 ? 5 : 4);
  const int m0 = xcd * 2048 + (li & MMSK) * BM;
  const int n0 = (li >> NSH) * 128;
  const int lane = t & 63, wave = t >> 6;
  const int wm = (wave >> 1) * (MI * 16), wn = (wave & 1) * 64;
  const int lr = lane & 15, quad = lane >> 4;
  // staging: lane -> row = lane>>2, phys chunk lane&3; gathers LOGICAL chunk
  // q = (lane&3) ^ (row&3) ^ ((lane>>4)&3)   [double-XOR swizzle]
  const int row8 = lane >> 2;
  const int qch = (((lane & 3) ^ (row8 & 3) ^ ((lane >> 4) & 3)) << 4);
  // fragment read offsets: phys chunk = (s*2+qh) ^ (lr&3) ^ ((lr>>2)&3)
  const int ql8 = (quad & 1) * 8, qh = quad >> 1;
  const int rx = (lr & 3) ^ ((lr >> 2) & 3);
  int koff[2];
#pragma unroll
  for (int s = 0; s < 2; ++s) koff[s] = (((s * 2 + qh) ^ rx) << 4) + ql8;

  // hoisted staging pointers (advance 64 B per K-iter)
  const unsigned char* gA0 = A + (size_t)(m0 + wave * (MI * 8) + row8) * LDA + qch;
  const unsigned char* gA1 = gA0 + (size_t)16 * LDA;  // chain only
  const unsigned char* gB0 = Bt + (size_t)(n0 + wave * 32 + row8) * LDA + qch;
  const unsigned char* gB1 = gB0 + (size_t)16 * LDA;

  auto stage = [&](int bufb) {
    if constexpr (EPI == 2) {
      gl2lds16(gA0, smem + bufb + wave * 1024);
    } else {
      gl2lds16(gA0, smem + bufb + wave * 2048);
      gl2lds16(gA1, smem + bufb + wave * 2048 + 1024);
      gA1 += 64;
    }
    gl2lds16(gB0, smem + bufb + ABYT + wave * 2048);
    gl2lds16(gB1, smem + bufb + ABYT + wave * 2048 + 1024);
    gA0 += 64; gB0 += 64; gB1 += 64;
  };

  f32x4 acc[MI][4] = {};
  f32x4 accf[EPI == 2 ? MI : 1][4] = {};  // EPI2 only: FiLM iter = X.Gc
  const int nt = Kdim >> 6;               // 17 for KD=1088

  // prologue: stage K-tile 0 into buffer 0
  stage(0);
  __syncthreads();

  int base = 0;
  for (int it = 0; it < nt; ++it) {
    const int nb = base ^ BUF;
    if (it + 1 < nt) stage(nb);  // prefetch next K-tile into other buffer
    const char* sA = (const char*)smem + base;
    const char* sB = sA + ABYT;
#pragma unroll
    for (int s = 0; s < 2; ++s) {  // two K=32 slices of the 64-B row
      long af[MI], bfr[4];
#pragma unroll
      for (int i = 0; i < MI; i++)
        af[i] = *(const long*)(sA + (wm + i * 16 + lr) * 64 + koff[s]);
#pragma unroll
      for (int j = 0; j < 4; j++)
        bfr[j] = *(const long*)(sB + (wn + j * 16 + lr) * 64 + koff[s]);
      if (EPI == 2 && it >= 16) {  // FiLM iter (k 1024..1087) -> accf
#pragma unroll
        for (int i = 0; i < MI; i++)
#pragma unroll
          for (int j = 0; j < 4; j++)
            accf[i][j] = __builtin_amdgcn_mfma_f32_16x16x32_fp8_fp8(af[i], bfr[j], accf[i][j], 0, 0, 0);
      } else {
#pragma unroll
        for (int i = 0; i < MI; i++)
#pragma unroll
          for (int j = 0; j < 4; j++)
            acc[i][j] = __builtin_amdgcn_mfma_f32_16x16x32_fp8_fp8(af[i], bfr[j], acc[i][j], 0, 0, 0);
      }
    }
    // ONE barrier per iter: its vmcnt(0) drain covers the prefetch (which
    // had the whole compute phase in flight); also proves all waves are done
    // reading `base` before it is re-staged next iteration. (R18's counted
    // vmcnt two-barrier variant measured neutral-to-worse — reverted.)
    __syncthreads();
    base = nb;
  }

  // per-thread cst values for this thread's 4 column slots (L1-resident)
  float cst_j[4];
  if constexpr (EPI != 2) {
#pragma unroll
    for (int j = 0; j < 4; j++) cst_j[j] = cst8[n0 + wn + j * 16 + lr];
  }

  // C/D layout (m89, dtype-independent): col = lane&15, row = quad*4 + reg
  if constexpr (EPI == 2) {
    if (n0 >= 1024) {  // bias-dot tile: cols 1024..1088 = [Gb-dots | cstb]
#pragma unroll
      for (int i = 0; i < MI; i++)
#pragma unroll
        for (int rg = 0; rg < 4; rg++) {
          const int r = m0 + wm + i * 16 + quad * 4 + rg;
          float pb = 0.f;
          if (wn == 0) {  // cg = j*16+lr in 0..63: G-dots with X[r]
#pragma unroll
            for (int j = 0; j < 4; j++)
              pb += acc[i][j][rg] * Xf[(size_t)r * 64 + j * 16 + lr];
          } else {        // col 1088 (j==0,lr==0): cst-dot
            if (lr == 0) pb = acc[i][0][rg];
          }
#pragma unroll
          for (int msk = 1; msk < 16; msk <<= 1) pb += __shfl_xor(pb, msk, 64);
          if (lr == 0) atomicAdd(&p2[r], pb);
        }
      return;
    }
    float cstc_j[4];
#pragma unroll
    for (int j = 0; j < 4; j++) cstc_j[j] = cst8[n0 + wn + j * 16 + lr];
#pragma unroll
    for (int i = 0; i < MI; i++)
#pragma unroll
      for (int rg = 0; rg < 4; rg++) {
        const int r = m0 + wm + i * 16 + quad * 4 + rg;
        bool uu = true;
        if (pv0 != nullptr) {
          const float dE = -pv0[r] + 2.f * pv1[r];
          uu = rng_u01(usalt, (unsigned)r) < sigm(dE);
        }
        float sn = 0.f, sf = 0.f;
#pragma unroll
        for (int j = 0; j < 4; j++) {
          const int n = n0 + wn + j * 16 + lr;
          const float vw = acc[i][j][rg];
          const float cm = accf[i][j][rg] + cstc_j[j];  // c_mod = X.Gc + cstc
          const float s1 = softplus_(vw + cm);
          const float s2 = softplus_(wcs[n] - vw + cm);
          sn += uu ? s1 : s2;
          sf += uu ? s2 : s1;
        }
#pragma unroll
        for (int msk = 1; msk < 16; msk <<= 1) {
          sn += __shfl_xor(sn, msk, 64);
          sf += __shfl_xor(sf, msk, 64);
        }
        if (lr == 0) { atomicAdd(&p0[r], sn); atomicAdd(&p1[r], sf); }
      }
    return;
  }

  if constexpr (EPI == 1) {  // z-sums with v from OLD s; u_t inline
#pragma unroll
    for (int i = 0; i < MI; i++)
#pragma unroll
      for (int rg = 0; rg < 4; rg++) {
        const int r = m0 + wm + i * 16 + quad * 4 + rg;
        const float dE = -pv0[r] + 2.f * pv1[r];
        const bool uu = rng_u01(usalt, (unsigned)r) < sigm(dE);
        float q0 = 0.f, q1 = 0.f;
#pragma unroll
        for (int j = 0; j < 4; ++j) {
          const float z = acc[i][j][rg] + cst_j[j];
          const float so = (sh[(size_t)r * LDA + n0 + wn + j * 16 + lr] != 0) ? 1.f : 0.f;
          const float v = uu ? so : 1.f - so;
          q0 += z; q1 += v * z;
        }
#pragma unroll
        for (int msk = 1; msk < 16; msk <<= 1) {
          q0 += __shfl_xor(q0, msk, 64);
          q1 += __shfl_xor(q1, msk, 64);
        }
        if (lr == 0) { atomicAdd(&p0[r], q0); atomicAdd(&p1[r], q1); }
      }
  }

  // EPI 0/1: sample into BM-row slab, 1 barrier, coalesced store
#pragma unroll
  for (int i = 0; i < MI; ++i)
#pragma unroll
    for (int rg = 0; rg < 4; ++rg) {
      const int rowl = wm + i * 16 + quad * 4 + rg;  // 0..BM-1 in tile
      const int r = m0 + rowl;
#pragma unroll
      for (int jp = 0; jp < 2; ++jp) {
        const unsigned x = hash32((unsigned)(r << 10) + (unsigned)(n0 + wn + jp * 16 + lr), salt);
        const float f0 = (float)(x & 0xFFFFu), f1 = (float)(x >> 16);
        const float z0 = acc[i][jp][rg] + cst_j[jp];
        const float z1v = acc[i][jp + 2][rg] + cst_j[jp + 2];
        newsl[rowl * SLS + wn + jp * 16 + lr] =
            (f0 * __expf(-z0) < 65536.f - f0) ? ONE8 : (unsigned char)0;
        newsl[rowl * SLS + wn + (jp + 2) * 16 + lr] =
            (f1 * __expf(-z1v) < 65536.f - f1) ? ONE8 : (unsigned char)0;
      }
    }
  __syncthreads();
#pragma unroll
  for (int p = 0; p < BM / 32; ++p) {  // BM rows x 128 B, fully coalesced
    const int c = p * 256 + t, rowl = c >> 3, chk = c & 7;
    const u32x4 vv = *(const u32x4*)(newsl + rowl * SLS + chk * 16);
    *(u32x4*)(sh + (size_t)(m0 + rowl) * LDA + n0 + chk * 16) = vv;
  }
}

// ------------------------- setup / small kernels ---------------------------
__global__ __launch_bounds__(256) void k_x(const float* __restrict__ cond,
                                           const float* __restrict__ fc1w,
                                           const float* __restrict__ fc1b, float* __restrict__ X) {
  int idx = blockIdx.x * 256 + threadIdx.x;
  int r = idx >> 6, k = idx & 63;
  X[idx] = tanhf(cond[r] * fc1w[k] + fc1b[k]);
}

__global__ __launch_bounds__(256) void k_g(const float* __restrict__ fc2w,
                                           const float* __restrict__ fc2b,
                                           const float* __restrict__ b, const float* __restrict__ c,
                                           float* __restrict__ Gb, float* __restrict__ Gc,
                                           float* __restrict__ cstb, float* __restrict__ cstc,
                                           float* __restrict__ cstb8, float* __restrict__ cstc8) {
  int idx = blockIdx.x * 256 + threadIdx.x;
  int j = idx >> 6, k = idx & 63;
  Gb[idx] = fc2w[(size_t)j * 64 + k] * b[j] + fc2w[(size_t)(1024 + j) * 64 + k];
  Gc[idx] = fc2w[(size_t)(2048 + j) * 64 + k] * c[j] + fc2w[(size_t)(3072 + j) * 64 + k];
  if (k == 0) {
    float vb = b[j] + fc2b[j] * b[j] + fc2b[1024 + j];
    float vc = c[j] + fc2b[2048 + j] * c[j] + fc2b[3072 + j];
    cstb[j] = vb; cstc[j] = vc;
    // fp8-roundtripped epilogue constants: identical value to what the
    // old K=1152 GEMM's cst column contributed (1.0 x e4m3(cst)).
    cstb8[j] = e4m3f(f2e4m3(vb));
    cstc8[j] = e4m3f(f2e4m3(vc));
  }
}

// Wt rows n<1024: [W^T|Gc|cstc|pad]; rows 1024..1088: [Gb-col profiles|cstb]
// (those rows are zero at k>=1024, so EPI2's accf==0 on the bias-dot tile).
// Wb rows n<1024: [W|Gb|cstb|pad]; rows beyond unused for Wb.
// (cst columns at k==1088 still written but never read: KD=1088.)
__global__ __launch_bounds__(256) void k_prep(const float* __restrict__ W,
                                              const float* __restrict__ Gb,
                                              const float* __restrict__ Gc,
                                              const float* __restrict__ cstb,
                                              const float* __restrict__ cstc,
                                              unsigned char* __restrict__ Wt,
                                              unsigned char* __restrict__ Wb) {
  int k = blockIdx.x * 256 + threadIdx.x;
  int n = blockIdx.y;
  if (k >= LDA) return;
  unsigned char wt = 0, wb = 0;
  if (n < 1024) {
    if (k < 1024) {
      wt = f2e4m3(W[(size_t)k * 1024 + n]);
      wb = f2e4m3(W[(size_t)n * 1024 + k]);
    } else if (k < 1088) {
      int j = k - 1024;
      wt = f2e4m3(Gc[(size_t)n * 64 + j]);
      wb = f2e4m3(Gb[(size_t)n * 64 + j]);
    } else if (k == 1088) {
      wt = f2e4m3(cstc[n]);
      wb = f2e4m3(cstb[n]);
    }
  } else if (k < 1024) {
    if (n < 1088) wt = f2e4m3(Gb[(size_t)k * 64 + (n - 1024)]);
    else if (n == 1088) wt = f2e4m3(cstb[k]);
  }
  Wt[(size_t)n * LDA + k] = wt;
  Wb[(size_t)n * LDA + k] = wb;
}

__global__ __launch_bounds__(256) void k_wcs(const float* __restrict__ W, float* __restrict__ wcs) {
  int n = blockIdx.x * 256 + threadIdx.x;
  float s = 0.f;
  for (int i = 0; i < 1024; i++) s += W[(size_t)i * 1024 + n];
  wcs[n] = s;
}

// aux[k<64] = sum_j Gb[j][k]; aux[64] = sum_j cstb[j]
__global__ __launch_bounds__(128) void k_aux(const float* __restrict__ Gb,
                                             const float* __restrict__ cstb,
                                             float* __restrict__ aux) {
  int t = threadIdx.x;
  if (t < 64) {
    float s = 0.f;
    for (int j = 0; j < 1024; j++) s += Gb[(size_t)j * 64 + t];
    aux[t] = s;
  } else if (t == 64) {
    float s = 0.f;
    for (int j = 0; j < 1024; j++) s += cstb[j];
    aux[64] = s;
  }
}

__global__ __launch_bounds__(256) void k_sinit(const float* __restrict__ vdata,
                                               const float* __restrict__ X,
                                               unsigned char* __restrict__ S,
                                               unsigned char* __restrict__ H,
                                               unsigned char* __restrict__ V) {
  int k = blockIdx.x * 256 + threadIdx.x;
  int r = blockIdx.y;
  if (k >= LDA) return;
  const size_t o = (size_t)r * LDA + k;
  if (k < 1024) {
    float vd = vdata[(size_t)r * 1024 + k];
    V[o] = (vd != 0.f) ? ONE8 : (unsigned char)0;
    const bool u0 = rng_u01(USALT, (unsigned)r) < 0.5f;  // == EPI1 step-0 formula
    float sv = u0 ? vd : 1.f - vd;
    S[o] = (sv != 0.f) ? ONE8 : (unsigned char)0;
  } else {
    unsigned char xv;
    if (k < 1088) xv = f2e4m3(X[(size_t)r * 64 + (k - 1024)]);
    else if (k == 1088) xv = ONE8;  // 1.0 (unused at KD=1088)
    else xv = 0;
    S[o] = xv; H[o] = xv; V[o] = xv;  // FiLM cols for K>=1024 GEMM iters
  }
}

// per-row scalar finale: sb from rank-64 closed form, d1/d2 from bias-dots
__global__ __launch_bounds__(256) void k_final(
    const float* __restrict__ Xf, const float* __restrict__ aux,
    const float* __restrict__ pv0, const float* __restrict__ pv1, unsigned usalt,
    const float* __restrict__ spn_d, const float* __restrict__ spf_d,
    const float* __restrict__ spn_m, const float* __restrict__ spf_m,
    const float* __restrict__ vb_d, const float* __restrict__ vb_m,
    float* __restrict__ fdiff) {
  __shared__ float ax[65];
  int t = threadIdx.x;
  if (t < 65) ax[t] = aux[t];
  __syncthreads();
  int r = blockIdx.x * 256 + t;
  float sb = ax[64];
  const float* xr = Xf + (size_t)r * 64;
#pragma unroll
  for (int k = 0; k < 64; k++) sb += xr[k] * ax[k];
  const float dE = -pv0[r] + 2.f * pv1[r];
  const bool uu = rng_u01(usalt, (unsigned)r) < sigm(dE);
  const float d1 = vb_d[r], d2 = vb_m[r];
  float F_d = -lse2(d1 + spn_d[r], (sb - d1) + spf_d[r]);
  float vbn = uu ? d2 : (sb - d2);
  float F_m = -lse2(vbn + spn_m[r], (sb - vbn) + spf_m[r]);
  fdiff[r] = F_d - F_m;
}

__global__ __launch_bounds__(256) void k_reduce(const float* __restrict__ fdiff,
                                                float* __restrict__ out) {
  __shared__ float red[4];
  int t = threadIdx.x;
  float s = 0.f;
  for (int i = t; i < NB; i += 256) s += fdiff[i];
  for (int m = 32; m >= 1; m >>= 1) s += __shfl_xor(s, m, 64);
  if ((t & 63) == 0) red[t >> 6] = s;
  __syncthreads();
  if (t == 0) out[0] = (red[0] + red[1] + red[2] + red[3]) * (1.0f / (float)NB);
}

// ---------------------------------------------------------------------------
extern "C" void kernel_launch(void* const* d_in, const int* in_sizes, int n_in, void* d_out,
                              int out_size, void* d_ws, size_t ws_size, hipStream_t stream) {
  const float* vdata = (const float*)d_in[0];
  const float* cond = (const float*)d_in[1];
  const float* W = (const float*)d_in[2];
  const float* bb = (const float*)d_in[3];
  const float* cc = (const float*)d_in[4];
  const float* fc1w = (const float*)d_in[5];
  const float* fc1b = (const float*)d_in[6];
  const float* fc2w = (const float*)d_in[7];
  const float* fc2b = (const float*)d_in[8];
  float* out = (float*)d_out;

  char* wp = (char*)d_ws;
  auto alloc = [&](size_t bytes) {
    char* p = wp;
    wp += (bytes + 255) & ~(size_t)255;
    return p;
  };
  unsigned char* Wt = (unsigned char*)alloc((size_t)1152 * LDA);
  unsigned char* Wb = (unsigned char*)alloc((size_t)1152 * LDA);
  float* wcs = (float*)alloc(1024 * 4);
  float* X = (float*)alloc((size_t)NB * 64 * 4);
  float* Gb = (float*)alloc((size_t)1024 * 64 * 4);
  float* Gc = (float*)alloc((size_t)1024 * 64 * 4);
  float* cstb = (float*)alloc(1024 * 4);
  float* cstc = (float*)alloc(1024 * 4);
  float* cstb8 = (float*)alloc(1024 * 4);
  float* cstc8 = (float*)alloc(1024 * 4);
  float* aux = (float*)alloc(65 * 4);
  unsigned char* S = (unsigned char*)alloc((size_t)NB * LDA);
  unsigned char* H = (unsigned char*)alloc((size_t)NB * LDA);
  unsigned char* V = (unsigned char*)alloc((size_t)NB * LDA);
  // per-step dE accumulators: pair t at pall + (t+1)*2*NB, t=-1..9; then 6 arrays
  float* pall = (float*)alloc((size_t)(KSTEPS + 1 + 3) * 2 * NB * 4);
  float* spn_d = pall + (size_t)(KSTEPS + 1) * 2 * NB;
  float* spf_d = spn_d + NB;
  float* spn_m = spf_d + NB;
  float* spf_m = spn_m + NB;
  float* vb_d = spf_m + NB;
  float* vb_m = vb_d + NB;
  float* fdiff = (float*)alloc(NB * 4);
  auto P0 = [&](int t) { return pall + (size_t)(t + 1) * 2 * NB; };
  auto P1 = [&](int t) { return pall + (size_t)(t + 1) * 2 * NB + NB; };

  hipMemsetAsync(pall, 0, (size_t)(KSTEPS + 1 + 3) * 2 * NB * 4, stream);

  k_x<<<NB * 64 / 256, 256, 0, stream>>>(cond, fc1w, fc1b, X);
  k_g<<<1024 * 64 / 256, 256, 0, stream>>>(fc2w, fc2b, bb, cc, Gb, Gc, cstb, cstc, cstb8, cstc8);
  k_prep<<<dim3(5, 1152), 256, 0, stream>>>(W, Gb, Gc, cstb, cstc, Wt, Wb);
  k_wcs<<<4, 256, 0, stream>>>(W, wcs);
  k_aux<<<1, 128, 0, stream>>>(Gb, cstb, aux);
  k_sinit<<<dim3(5, NB), 256, 0, stream>>>(vdata, X, S, H, V);

  for (int step = 0; step < KSTEPS; ++step) {
    // z1 = sW + c_mod (ext-K, +cstc8 epi); h ~ Bern(sigm(z1)) -> H
    gemm_bt<0><<<1024, 256, 0, stream>>>(S, Wt, H, cstc8, nullptr, nullptr,
                                         nullptr, nullptr, 0u, nullptr, nullptr, nullptr,
                                         2000u + (unsigned)step, KD);
    // z2 = hW^T + b_mod (ext-K, +cstb8 epi); u_t inline; dE partials; s_new -> S
    gemm_bt<1><<<1024, 256, 0, stream>>>(H, Wb, S, cstb8, nullptr, nullptr,
                                         P0(step - 1), P1(step - 1), USALT + (unsigned)step,
                                         P0(step), P1(step), nullptr,
                                         3000u + (unsigned)step, KD);
  }

  // Free-energy: softplus rows (n-tiles 0..7, split-acc; cm = accf+cstc8) +
  // bias-dots (n-tile 8). cmod table eliminated (R16); cst via epilogue (R19).
  gemm_bt<2><<<2304, 256, 0, stream>>>(V, Wt, nullptr, cstc8, wcs, X, nullptr, nullptr, 0u,
                                       spn_d, spf_d, vb_d, 0u, KD);
  gemm_bt<2><<<2304, 256, 0, stream>>>(S, Wt, nullptr, cstc8, wcs, X,
                                       P0(KSTEPS - 1), P1(KSTEPS - 1), USALT + KSTEPS,
                                       spn_m, spf_m, vb_m, 0u, KD);
  k_final<<<NB / 256, 256, 0, stream>>>(X, aux, P0(KSTEPS - 1), P1(KSTEPS - 1), USALT + KSTEPS,
                                        spn_d, spf_d, spn_m, spf_m, vb_d, vb_m, fdiff);
  k_reduce<<<1, 256, 0, stream>>>(fdiff, out);
}

// Round 7
// 1018.773 us; speedup vs baseline: 1.0580x; 1.0213x over previous
//
#include <hip/hip_runtime.h>
#include <hip/hip_bf16.h>
#include <stdint.h>

// SymmetricHyperRBM on MI355X. K=10 Gibbs chain + free-energy gap.
// fp8 e4m3; FiLM biases folded into GEMM K-dim; XCD swizzle; inline-u chain.
// R20: (a) compile-time K-loop (NT=17, full unroll): ds_read/global_load_lds
// offsets become immediates, FiLM branch resolves at compile time — cuts the
// ~40 VALU ops/iter/wave of dynamic addressing (VALUBusy was 60%).
// (b) EPI1 old-S reads: was 64 scattered global_load_ubyte per thread
// (4096 byte-requests/wave into L2); now gl2lds-stage the block's own
// 128x128 old-S tile into the dead buffer-1 region with PRE-SWIZZLED global
// source (m173: lds chunk c of row r <- glob chunk c^((r>>2)&3)), read so
// via ds_read_u8 (4-way conflict by design; read swz = quad). One extra
// barrier before slab writes (slab overlaps old-S region; consumed by then).
// R19 carried: KD=1088, cst in epilogue; single __syncthreads/iter (R18's
// counted-vmcnt two-barrier measured worse). R17: chain BM=128 4x(64x64).
// R16: EPI2 split-acc, cmod/k_bmod eliminated. R15: stage-ahead dbuf.

#define NB 16384
#define KSTEPS 10
#define LDA 1152           // bytes/row: 1024 state + 64 X + 1 const + 63 pad
#define KD 1088            // GEMM K-dim: 1024 state + 64 X (cst in epilogue)
#define NT 17              // KD/64 K-iterations (compile-time, fully unrolled)
#define SLS 136            // epilogue slab row stride in bytes (128 + 8 pad)
#define USALT 4000u
#define ONE8 ((unsigned char)0x38)  // fp8 e4m3 1.0

typedef __attribute__((ext_vector_type(4))) float f32x4;
typedef __attribute__((ext_vector_type(4))) unsigned int u32x4;

__device__ __forceinline__ unsigned hash32(unsigned idx, unsigned salt) {
  unsigned x = idx + salt * 0x9E3779B9u;
  x = (x ^ (x >> 16)) * 0x7feb352du;
  x = (x ^ (x >> 15)) * 0x846ca68bu;
  return x ^ (x >> 16);
}
__device__ __forceinline__ float rng_u01(unsigned salt, unsigned idx) {
  return (float)(hash32(idx, salt) >> 8) * (1.0f / 16777216.0f);
}
__device__ __forceinline__ float sigm(float z) { return 1.0f / (1.0f + __expf(-z)); }
// fast softplus: max(z,0) + log(1+exp(-|z|)); v_exp/v_log based.
__device__ __forceinline__ float softplus_(float z) {
  return fmaxf(z, 0.f) + __logf(1.f + __expf(-fabsf(z)));
}
__device__ __forceinline__ float lse2(float a, float b) {
  float m = fmaxf(a, b);
  return m + log1pf(__expf(fminf(a, b) - m));
}
__device__ __forceinline__ float bf2f(unsigned short s) {
  unsigned u = ((unsigned)s) << 16;
  return *reinterpret_cast<float*>(&u);
}
__device__ __forceinline__ unsigned short f2bf(float f) {
  __hip_bfloat16 h = __float2bfloat16(f);
  return *reinterpret_cast<unsigned short*>(&h);
}
// float -> fp8 e4m3fn (OCP), RNE, saturating. Setup-path only.
__device__ unsigned char f2e4m3(float f) {
  unsigned u = __float_as_uint(f);
  unsigned char s = (unsigned char)((u >> 24) & 0x80);
  float af = fabsf(f);
  if (af >= 448.f) return s | 0x7E;
  float sub = rintf(af * 512.f);
  if (sub < 1.f) return s;                 // underflow -> 0
  if (af < 0.015625f) {                    // subnormal, step 2^-9
    int m = (int)sub;
    if (m > 7) return s | 0x08;
    return s | (unsigned char)m;
  }
  int ex; frexpf(af, &ex);
  int E = ex - 1;                          // af in [2^E, 2^(E+1))
  float q = rintf(ldexpf(af, 3 - E));      // in [8,16]
  int qi = (int)q;
  if (qi >= 16) { qi = 8; E += 1; if (E > 8) return s | 0x7E; }
  return s | (unsigned char)(((E + 7) << 3) | (qi - 8));
}
// e4m3fn -> float (epilogue cst: value == what the GEMM would have added)
__device__ __forceinline__ float e4m3f(unsigned char v) {
  float s = (v & 0x80) ? -1.f : 1.f;
  int e = (v >> 3) & 15, m = v & 7;
  float mag = e ? ldexpf((float)(8 + m), e - 10) : ldexpf((float)m, -9);
  return s * mag;
}
__device__ __forceinline__ void gl2lds16(const void* g, void* l) {
  __builtin_amdgcn_global_load_lds(
      (const __attribute__((address_space(1))) unsigned int*)g,
      (__attribute__((address_space(3))) unsigned int*)l, 16, 0, 0);
}

// ---------------------------------------------------------------------------
// C = A[16384 x KD] * Bt[. x KD]^T (+cst8[n] in epilogue), fp8 MFMA 16x16x32,
// BK=64, NT=17 fully unrolled, double-buffered LDS, ONE barrier/iter.
// Chain (EPI0/1): BM=128 tile, 4 waves x 64x64, grid 1024:
//   xcd=L&7, li=L>>3; m0 = xcd*2048 + (li&15)*128; n-tile = li>>4.
// EPI2: BM=64 tile, 4 waves x 32x64, grid 2304 (incl. bias n-tile 8):
//   m0 = xcd*2048 + (li&31)*64; n-tile = li>>5.
// EPI 0: h = bern(sigm(z1)) -> sh, z1 = acc + cstc8[n].
// EPI 1: u_t inline; p0+=sum z, p1+=sum v*z (v via LDS-staged old-S tile);
//        s_new -> sh.
// EPI 2: split-acc (acc: it<16 = vW; accf: it==16 = X.Gc); cm = accf+cstc8.
//        n<8: softplus rows -> p0,p1; n==8: bias-dots (acc . X -> p2).
// ---------------------------------------------------------------------------
template <int EPI>
__global__ __launch_bounds__(256, 4) void gemm_bt(
    const unsigned char* __restrict__ A, const unsigned char* __restrict__ Bt,
    unsigned char* sh, const float* __restrict__ cst8,
    const float* __restrict__ wcs, const float* __restrict__ Xf,
    const float* __restrict__ pv0, const float* __restrict__ pv1, unsigned usalt,
    float* __restrict__ p0, float* __restrict__ p1, float* __restrict__ p2,
    unsigned salt) {
  constexpr int MI = (EPI == 2 ? 2 : 4);   // 16-row tiles per wave (M dir)
  constexpr int BM = MI * 32;              // block rows: 64 (EPI2) / 128
  constexpr int ABYT = BM * 64;            // A-panel bytes/buffer: 4K / 8K
  constexpr int BUF = ABYT + 8192;         // buffer stride: 12K / 16K
  // epilogue slab BM x 136 B aliases the front after the loop (chain only);
  // EPI1 stages the old-S tile (BM x 128 B) into the buffer-1 region.
  __shared__ __align__(16) char smem[2 * BUF];
  unsigned char* newsl = (unsigned char*)smem;

  const int t = threadIdx.x;
  const int L = blockIdx.x;
  const int xcd = L & 7, li = L >> 3;
  constexpr int MMSK = (EPI == 2 ? 31 : 15);
  constexpr int NSH = (EPI == 2 ? 5 : 4);
  const int m0 = xcd * 2048 + (li & MMSK) * BM;
  const int n0 = (li >> NSH) * 128;
  const int lane = t & 63, wave = t >> 6;
  const int wm = (wave >> 1) * (MI * 16), wn = (wave & 1) * 64;
  const int lr = lane & 15, quad = lane >> 4;
  // staging: lane -> row = lane>>2, phys chunk lane&3; gathers LOGICAL chunk
  // q = (lane&3) ^ (row&3) ^ ((lane>>4)&3)   [double-XOR swizzle]
  const int row8 = lane >> 2;
  const int qch = (((lane & 3) ^ (row8 & 3) ^ ((lane >> 4) & 3)) << 4);
  // fragment read offsets: phys chunk = (s*2+qh) ^ (lr&3) ^ ((lr>>2)&3)
  const int ql8 = (quad & 1) * 8, qh = quad >> 1;
  const int rx = (lr & 3) ^ ((lr >> 2) & 3);
  int koff[2];
#pragma unroll
  for (int s = 0; s < 2; ++s) koff[s] = (((s * 2 + qh) ^ rx) << 4) + ql8;

  // staging base pointers; per-iter advance folds to immediates (unrolled)
  const unsigned char* gA0 = A + (size_t)(m0 + wave * (MI * 8) + row8) * LDA + qch;
  const unsigned char* gA1 = gA0 + (size_t)16 * LDA;  // chain only
  const unsigned char* gB0 = Bt + (size_t)(n0 + wave * 32 + row8) * LDA + qch;
  const unsigned char* gB1 = gB0 + (size_t)16 * LDA;

  auto stage = [&](int it, int bufb) {
    const int ko = it * 64;
    if constexpr (EPI == 2) {
      gl2lds16(gA0 + ko, smem + bufb + wave * 1024);
    } else {
      gl2lds16(gA0 + ko, smem + bufb + wave * 2048);
      gl2lds16(gA1 + ko, smem + bufb + wave * 2048 + 1024);
    }
    gl2lds16(gB0 + ko, smem + bufb + ABYT + wave * 2048);
    gl2lds16(gB1 + ko, smem + bufb + ABYT + wave * 2048 + 1024);
  };

  f32x4 acc[MI][4] = {};
  f32x4 accf[EPI == 2 ? MI : 1][4] = {};  // EPI2 only: FiLM iter = X.Gc

  // prologue: stage K-tile 0 into buffer 0
  stage(0, 0);
  __syncthreads();

#pragma unroll
  for (int it = 0; it < NT; ++it) {
    const int base = (it & 1) * BUF;          // compile-time per body
    if (it + 1 < NT) stage(it + 1, base ^ BUF);
    const char* sA = (const char*)smem + base;
    const char* sB = sA + ABYT;
#pragma unroll
    for (int s = 0; s < 2; ++s) {  // two K=32 slices of the 64-B row
      long af[MI], bfr[4];
#pragma unroll
      for (int i = 0; i < MI; i++)
        af[i] = *(const long*)(sA + (wm + i * 16 + lr) * 64 + koff[s]);
#pragma unroll
      for (int j = 0; j < 4; j++)
        bfr[j] = *(const long*)(sB + (wn + j * 16 + lr) * 64 + koff[s]);
      if (EPI == 2 && it >= 16) {  // FiLM iter (k 1024..1087) -> accf
#pragma unroll
        for (int i = 0; i < MI; i++)
#pragma unroll
          for (int j = 0; j < 4; j++)
            accf[i][j] = __builtin_amdgcn_mfma_f32_16x16x32_fp8_fp8(af[i], bfr[j], accf[i][j], 0, 0, 0);
      } else {
#pragma unroll
        for (int i = 0; i < MI; i++)
#pragma unroll
          for (int j = 0; j < 4; j++)
            acc[i][j] = __builtin_amdgcn_mfma_f32_16x16x32_fp8_fp8(af[i], bfr[j], acc[i][j], 0, 0, 0);
      }
    }
    // ONE barrier per iter: its vmcnt(0) drain covers the prefetch (in
    // flight across the whole compute phase) and orders reads-of-base
    // before the next overwrite.
    __syncthreads();
  }

  // per-thread cst values for this thread's 4 column slots (L1-resident)
  float cst_j[4];
  if constexpr (EPI != 2) {
#pragma unroll
    for (int j = 0; j < 4; j++) cst_j[j] = cst8[n0 + wn + j * 16 + lr];
  }

  // C/D layout (m89, dtype-independent): col = lane&15, row = quad*4 + reg
  if constexpr (EPI == 2) {
    if (n0 >= 1024) {  // bias-dot tile: cols 1024..1088 = [Gb-dots | cstb]
#pragma unroll
      for (int i = 0; i < MI; i++)
#pragma unroll
        for (int rg = 0; rg < 4; rg++) {
          const int r = m0 + wm + i * 16 + quad * 4 + rg;
          float pb = 0.f;
          if (wn == 0) {  // cg = j*16+lr in 0..63: G-dots with X[r]
#pragma unroll
            for (int j = 0; j < 4; j++)
              pb += acc[i][j][rg] * Xf[(size_t)r * 64 + j * 16 + lr];
          } else {        // col 1088 (j==0,lr==0): cst-dot
            if (lr == 0) pb = acc[i][0][rg];
          }
#pragma unroll
          for (int msk = 1; msk < 16; msk <<= 1) pb += __shfl_xor(pb, msk, 64);
          if (lr == 0) atomicAdd(&p2[r], pb);
        }
      return;
    }
    float cstc_j[4];
#pragma unroll
    for (int j = 0; j < 4; j++) cstc_j[j] = cst8[n0 + wn + j * 16 + lr];
#pragma unroll
    for (int i = 0; i < MI; i++)
#pragma unroll
      for (int rg = 0; rg < 4; rg++) {
        const int r = m0 + wm + i * 16 + quad * 4 + rg;
        bool uu = true;
        if (pv0 != nullptr) {
          const float dE = -pv0[r] + 2.f * pv1[r];
          uu = rng_u01(usalt, (unsigned)r) < sigm(dE);
        }
        float sn = 0.f, sf = 0.f;
#pragma unroll
        for (int j = 0; j < 4; j++) {
          const int n = n0 + wn + j * 16 + lr;
          const float vw = acc[i][j][rg];
          const float cm = accf[i][j][rg] + cstc_j[j];  // c_mod = X.Gc + cstc
          const float s1 = softplus_(vw + cm);
          const float s2 = softplus_(wcs[n] - vw + cm);
          sn += uu ? s1 : s2;
          sf += uu ? s2 : s1;
        }
#pragma unroll
        for (int msk = 1; msk < 16; msk <<= 1) {
          sn += __shfl_xor(sn, msk, 64);
          sf += __shfl_xor(sf, msk, 64);
        }
        if (lr == 0) { atomicAdd(&p0[r], sn); atomicAdd(&p1[r], sf); }
      }
    return;
  }

  if constexpr (EPI == 1) {  // z-sums with v from OLD s; u_t inline
    // Stage this block's OLD-S tile (BM x 128 B) into the buffer-1 region
    // (dead after the loop: last tile computed in buffer 0 since NT odd).
    // m173 pattern: linear LDS dest + PRE-SWIZZLED global source, so that
    // lds chunk c of row r holds global chunk c ^ ((r>>2)&3).
    {
      const int rb = wave * (MI * 8);            // 32 rows per wave (BM=128)
#pragma unroll
      for (int q = 0; q < MI; ++q) {
        const int row = rb + q * 8 + (lane >> 3);
        const int sc = (lane & 7) ^ ((row >> 2) & 3);
        gl2lds16(sh + (size_t)(m0 + row) * LDA + n0 + sc * 16,
                 (unsigned char*)smem + BUF + (rb + q * 8) * 128);
      }
    }
    __syncthreads();  // drains vmcnt -> old-S tile published in LDS
    const unsigned char* osl = (const unsigned char*)smem + BUF;
#pragma unroll
    for (int i = 0; i < MI; i++)
#pragma unroll
      for (int rg = 0; rg < 4; rg++) {
        const int r = m0 + wm + i * 16 + quad * 4 + rg;
        const int rowl = wm + i * 16 + quad * 4 + rg;
        const float dE = -pv0[r] + 2.f * pv1[r];
        const bool uu = rng_u01(usalt, (unsigned)r) < sigm(dE);
        float q0 = 0.f, q1 = 0.f;
#pragma unroll
        for (int j = 0; j < 4; ++j) {
          const float z = acc[i][j][rg] + cst_j[j];
          // read-side swizzle: (rowl>>2)&3 == quad for our row decomposition
          const int pc = ((wn >> 4) + j) ^ quad;
          const float so = (osl[rowl * 128 + pc * 16 + lr] != 0) ? 1.f : 0.f;
          const float v = uu ? so : 1.f - so;
          q0 += z; q1 += v * z;
        }
#pragma unroll
        for (int msk = 1; msk < 16; msk <<= 1) {
          q0 += __shfl_xor(q0, msk, 64);
          q1 += __shfl_xor(q1, msk, 64);
        }
        if (lr == 0) { atomicAdd(&p0[r], q0); atomicAdd(&p1[r], q1); }
      }
    __syncthreads();  // all old-S reads done before slab overwrites [BUF,..)
  }

  // EPI 0/1: sample into BM-row slab, 1 barrier, coalesced store
#pragma unroll
  for (int i = 0; i < MI; ++i)
#pragma unroll
    for (int rg = 0; rg < 4; ++rg) {
      const int rowl = wm + i * 16 + quad * 4 + rg;  // 0..BM-1 in tile
      const int r = m0 + rowl;
#pragma unroll
      for (int jp = 0; jp < 2; ++jp) {
        const unsigned x = hash32((unsigned)(r << 10) + (unsigned)(n0 + wn + jp * 16 + lr), salt);
        const float f0 = (float)(x & 0xFFFFu), f1 = (float)(x >> 16);
        const float z0 = acc[i][jp][rg] + cst_j[jp];
        const float z1v = acc[i][jp + 2][rg] + cst_j[jp + 2];
        newsl[rowl * SLS + wn + jp * 16 + lr] =
            (f0 * __expf(-z0) < 65536.f - f0) ? ONE8 : (unsigned char)0;
        newsl[rowl * SLS + wn + (jp + 2) * 16 + lr] =
            (f1 * __expf(-z1v) < 65536.f - f1) ? ONE8 : (unsigned char)0;
      }
    }
  __syncthreads();
#pragma unroll
  for (int p = 0; p < BM / 32; ++p) {  // BM rows x 128 B, fully coalesced
    const int c = p * 256 + t, rowl = c >> 3, chk = c & 7;
    const u32x4 vv = *(const u32x4*)(newsl + rowl * SLS + chk * 16);
    *(u32x4*)(sh + (size_t)(m0 + rowl) * LDA + n0 + chk * 16) = vv;
  }
}

// ------------------------- setup / small kernels ---------------------------
__global__ __launch_bounds__(256) void k_x(const float* __restrict__ cond,
                                           const float* __restrict__ fc1w,
                                           const float* __restrict__ fc1b, float* __restrict__ X) {
  int idx = blockIdx.x * 256 + threadIdx.x;
  int r = idx >> 6, k = idx & 63;
  X[idx] = tanhf(cond[r] * fc1w[k] + fc1b[k]);
}

__global__ __launch_bounds__(256) void k_g(const float* __restrict__ fc2w,
                                           const float* __restrict__ fc2b,
                                           const float* __restrict__ b, const float* __restrict__ c,
                                           float* __restrict__ Gb, float* __restrict__ Gc,
                                           float* __restrict__ cstb, float* __restrict__ cstc,
                                           float* __restrict__ cstb8, float* __restrict__ cstc8) {
  int idx = blockIdx.x * 256 + threadIdx.x;
  int j = idx >> 6, k = idx & 63;
  Gb[idx] = fc2w[(size_t)j * 64 + k] * b[j] + fc2w[(size_t)(1024 + j) * 64 + k];
  Gc[idx] = fc2w[(size_t)(2048 + j) * 64 + k] * c[j] + fc2w[(size_t)(3072 + j) * 64 + k];
  if (k == 0) {
    float vb = b[j] + fc2b[j] * b[j] + fc2b[1024 + j];
    float vc = c[j] + fc2b[2048 + j] * c[j] + fc2b[3072 + j];
    cstb[j] = vb; cstc[j] = vc;
    // fp8-roundtripped epilogue constants: identical value to what the
    // old K=1152 GEMM's cst column contributed (1.0 x e4m3(cst)).
    cstb8[j] = e4m3f(f2e4m3(vb));
    cstc8[j] = e4m3f(f2e4m3(vc));
  }
}

// Wt rows n<1024: [W^T|Gc|cstc|pad]; rows 1024..1088: [Gb-col profiles|cstb]
// (those rows are zero at k>=1024, so EPI2's accf==0 on the bias-dot tile).
// Wb rows n<1024: [W|Gb|cstb|pad]; rows beyond unused for Wb.
// (cst columns at k==1088 still written but never read: KD=1088.)
__global__ __launch_bounds__(256) void k_prep(const float* __restrict__ W,
                                              const float* __restrict__ Gb,
                                              const float* __restrict__ Gc,
                                              const float* __restrict__ cstb,
                                              const float* __restrict__ cstc,
                                              unsigned char* __restrict__ Wt,
                                              unsigned char* __restrict__ Wb) {
  int k = blockIdx.x * 256 + threadIdx.x;
  int n = blockIdx.y;
  if (k >= LDA) return;
  unsigned char wt = 0, wb = 0;
  if (n < 1024) {
    if (k < 1024) {
      wt = f2e4m3(W[(size_t)k * 1024 + n]);
      wb = f2e4m3(W[(size_t)n * 1024 + k]);
    } else if (k < 1088) {
      int j = k - 1024;
      wt = f2e4m3(Gc[(size_t)n * 64 + j]);
      wb = f2e4m3(Gb[(size_t)n * 64 + j]);
    } else if (k == 1088) {
      wt = f2e4m3(cstc[n]);
      wb = f2e4m3(cstb[n]);
    }
  } else if (k < 1024) {
    if (n < 1088) wt = f2e4m3(Gb[(size_t)k * 64 + (n - 1024)]);
    else if (n == 1088) wt = f2e4m3(cstb[k]);
  }
  Wt[(size_t)n * LDA + k] = wt;
  Wb[(size_t)n * LDA + k] = wb;
}

__global__ __launch_bounds__(256) void k_wcs(const float* __restrict__ W, float* __restrict__ wcs) {
  int n = blockIdx.x * 256 + threadIdx.x;
  float s = 0.f;
  for (int i = 0; i < 1024; i++) s += W[(size_t)i * 1024 + n];
  wcs[n] = s;
}

// aux[k<64] = sum_j Gb[j][k]; aux[64] = sum_j cstb[j]
__global__ __launch_bounds__(128) void k_aux(const float* __restrict__ Gb,
                                             const float* __restrict__ cstb,
                                             float* __restrict__ aux) {
  int t = threadIdx.x;
  if (t < 64) {
    float s = 0.f;
    for (int j = 0; j < 1024; j++) s += Gb[(size_t)j * 64 + t];
    aux[t] = s;
  } else if (t == 64) {
    float s = 0.f;
    for (int j = 0; j < 1024; j++) s += cstb[j];
    aux[64] = s;
  }
}

__global__ __launch_bounds__(256) void k_sinit(const float* __restrict__ vdata,
                                               const float* __restrict__ X,
                                               unsigned char* __restrict__ S,
                                               unsigned char* __restrict__ H,
                                               unsigned char* __restrict__ V) {
  int k = blockIdx.x * 256 + threadIdx.x;
  int r = blockIdx.y;
  if (k >= LDA) return;
  const size_t o = (size_t)r * LDA + k;
  if (k < 1024) {
    float vd = vdata[(size_t)r * 1024 + k];
    V[o] = (vd != 0.f) ? ONE8 : (unsigned char)0;
    const bool u0 = rng_u01(USALT, (unsigned)r) < 0.5f;  // == EPI1 step-0 formula
    float sv = u0 ? vd : 1.f - vd;
    S[o] = (sv != 0.f) ? ONE8 : (unsigned char)0;
  } else {
    unsigned char xv;
    if (k < 1088) xv = f2e4m3(X[(size_t)r * 64 + (k - 1024)]);
    else if (k == 1088) xv = ONE8;  // 1.0 (unused at KD=1088)
    else xv = 0;
    S[o] = xv; H[o] = xv; V[o] = xv;  // FiLM cols for K>=1024 GEMM iters
  }
}

// per-row scalar finale: sb from rank-64 closed form, d1/d2 from bias-dots
__global__ __launch_bounds__(256) void k_final(
    const float* __restrict__ Xf, const float* __restrict__ aux,
    const float* __restrict__ pv0, const float* __restrict__ pv1, unsigned usalt,
    const float* __restrict__ spn_d, const float* __restrict__ spf_d,
    const float* __restrict__ spn_m, const float* __restrict__ spf_m,
    const float* __restrict__ vb_d, const float* __restrict__ vb_m,
    float* __restrict__ fdiff) {
  __shared__ float ax[65];
  int t = threadIdx.x;
  if (t < 65) ax[t] = aux[t];
  __syncthreads();
  int r = blockIdx.x * 256 + t;
  float sb = ax[64];
  const float* xr = Xf + (size_t)r * 64;
#pragma unroll
  for (int k = 0; k < 64; k++) sb += xr[k] * ax[k];
  const float dE = -pv0[r] + 2.f * pv1[r];
  const bool uu = rng_u01(usalt, (unsigned)r) < sigm(dE);
  const float d1 = vb_d[r], d2 = vb_m[r];
  float F_d = -lse2(d1 + spn_d[r], (sb - d1) + spf_d[r]);
  float vbn = uu ? d2 : (sb - d2);
  float F_m = -lse2(vbn + spn_m[r], (sb - vbn) + spf_m[r]);
  fdiff[r] = F_d - F_m;
}

__global__ __launch_bounds__(256) void k_reduce(const float* __restrict__ fdiff,
                                                float* __restrict__ out) {
  __shared__ float red[4];
  int t = threadIdx.x;
  float s = 0.f;
  for (int i = t; i < NB; i += 256) s += fdiff[i];
  for (int m = 32; m >= 1; m >>= 1) s += __shfl_xor(s, m, 64);
  if ((t & 63) == 0) red[t >> 6] = s;
  __syncthreads();
  if (t == 0) out[0] = (red[0] + red[1] + red[2] + red[3]) * (1.0f / (float)NB);
}

// ---------------------------------------------------------------------------
extern "C" void kernel_launch(void* const* d_in, const int* in_sizes, int n_in, void* d_out,
                              int out_size, void* d_ws, size_t ws_size, hipStream_t stream) {
  const float* vdata = (const float*)d_in[0];
  const float* cond = (const float*)d_in[1];
  const float* W = (const float*)d_in[2];
  const float* bb = (const float*)d_in[3];
  const float* cc = (const float*)d_in[4];
  const float* fc1w = (const float*)d_in[5];
  const float* fc1b = (const float*)d_in[6];
  const float* fc2w = (const float*)d_in[7];
  const float* fc2b = (const float*)d_in[8];
  float* out = (float*)d_out;

  char* wp = (char*)d_ws;
  auto alloc = [&](size_t bytes) {
    char* p = wp;
    wp += (bytes + 255) & ~(size_t)255;
    return p;
  };
  unsigned char* Wt = (unsigned char*)alloc((size_t)1152 * LDA);
  unsigned char* Wb = (unsigned char*)alloc((size_t)1152 * LDA);
  float* wcs = (float*)alloc(1024 * 4);
  float* X = (float*)alloc((size_t)NB * 64 * 4);
  float* Gb = (float*)alloc((size_t)1024 * 64 * 4);
  float* Gc = (float*)alloc((size_t)1024 * 64 * 4);
  float* cstb = (float*)alloc(1024 * 4);
  float* cstc = (float*)alloc(1024 * 4);
  float* cstb8 = (float*)alloc(1024 * 4);
  float* cstc8 = (float*)alloc(1024 * 4);
  float* aux = (float*)alloc(65 * 4);
  unsigned char* S = (unsigned char*)alloc((size_t)NB * LDA);
  unsigned char* H = (unsigned char*)alloc((size_t)NB * LDA);
  unsigned char* V = (unsigned char*)alloc((size_t)NB * LDA);
  // per-step dE accumulators: pair t at pall + (t+1)*2*NB, t=-1..9; then 6 arrays
  float* pall = (float*)alloc((size_t)(KSTEPS + 1 + 3) * 2 * NB * 4);
  float* spn_d = pall + (size_t)(KSTEPS + 1) * 2 * NB;
  float* spf_d = spn_d + NB;
  float* spn_m = spf_d + NB;
  float* spf_m = spn_m + NB;
  float* vb_d = spf_m + NB;
  float* vb_m = vb_d + NB;
  float* fdiff = (float*)alloc(NB * 4);
  auto P0 = [&](int t) { return pall + (size_t)(t + 1) * 2 * NB; };
  auto P1 = [&](int t) { return pall + (size_t)(t + 1) * 2 * NB + NB; };

  hipMemsetAsync(pall, 0, (size_t)(KSTEPS + 1 + 3) * 2 * NB * 4, stream);

  k_x<<<NB * 64 / 256, 256, 0, stream>>>(cond, fc1w, fc1b, X);
  k_g<<<1024 * 64 / 256, 256, 0, stream>>>(fc2w, fc2b, bb, cc, Gb, Gc, cstb, cstc, cstb8, cstc8);
  k_prep<<<dim3(5, 1152), 256, 0, stream>>>(W, Gb, Gc, cstb, cstc, Wt, Wb);
  k_wcs<<<4, 256, 0, stream>>>(W, wcs);
  k_aux<<<1, 128, 0, stream>>>(Gb, cstb, aux);
  k_sinit<<<dim3(5, NB), 256, 0, stream>>>(vdata, X, S, H, V);

  for (int step = 0; step < KSTEPS; ++step) {
    // z1 = sW + c_mod (ext-K, +cstc8 epi); h ~ Bern(sigm(z1)) -> H
    gemm_bt<0><<<1024, 256, 0, stream>>>(S, Wt, H, cstc8, nullptr, nullptr,
                                         nullptr, nullptr, 0u, nullptr, nullptr, nullptr,
                                         2000u + (unsigned)step);
    // z2 = hW^T + b_mod (ext-K, +cstb8 epi); u_t inline; dE partials; s_new -> S
    gemm_bt<1><<<1024, 256, 0, stream>>>(H, Wb, S, cstb8, nullptr, nullptr,
                                         P0(step - 1), P1(step - 1), USALT + (unsigned)step,
                                         P0(step), P1(step), nullptr,
                                         3000u + (unsigned)step);
  }

  // Free-energy: softplus rows (n-tiles 0..7, split-acc; cm = accf+cstc8) +
  // bias-dots (n-tile 8). cmod table eliminated (R16); cst via epilogue (R19).
  gemm_bt<2><<<2304, 256, 0, stream>>>(V, Wt, nullptr, cstc8, wcs, X, nullptr, nullptr, 0u,
                                       spn_d, spf_d, vb_d, 0u);
  gemm_bt<2><<<2304, 256, 0, stream>>>(S, Wt, nullptr, cstc8, wcs, X,
                                       P0(KSTEPS - 1), P1(KSTEPS - 1), USALT + KSTEPS,
                                       spn_m, spf_m, vb_m, 0u);
  k_final<<<NB / 256, 256, 0, stream>>>(X, aux, P0(KSTEPS - 1), P1(KSTEPS - 1), USALT + KSTEPS,
                                        spn_d, spf_d, spn_m, spf_m, vb_d, vb_m, fdiff);
  k_reduce<<<1, 256, 0, stream>>>(fdiff, out);
}

// Round 8
// 1002.799 us; speedup vs baseline: 1.0748x; 1.0159x over previous
//
#include <hip/hip_runtime.h>
#include <hip/hip_bf16.h>
#include <stdint.h>

// SymmetricHyperRBM on MI355X. K=10 Gibbs chain + free-energy gap.
// R21: i8 MFMA (mfma_i32_16x16x64_i8, K=64/inst, ~2x fp8 rate). States
// binary {0,7}; w_int=round(W*8192/7); x_int=round(X*128); g_int=round(G*64);
// common scale p=2^-13 makes the chain's single int accumulator valid:
// 7*w_int*p = W, x_int*g_int*p = X*G. Epilogue z = (float)acc*p + cst(fp32).
// Bias-dot tile: per-branch scales (G-cols /448, cst col *p). Fragments are
// 16 contiguous k-bytes/lane at logical chunk=quad -> one ds_read_b128 via
// the same double-XOR swizzle (phys = quad^rx). i8 quantization here is
// equal-or-better than e4m3 (W step 8.5e-4 vs ~9.8e-4). i32 accum is exact.
// R20 carried: NT=17 full unroll; EPI1 old-S via LDS-staged swizzled tile.
// R19: KD=1088, cst in epilogue; single __syncthreads/iter. R17: chain
// BM=128 4x(64x64). R16: EPI2 split-acc. R15: stage-ahead dbuf.

#define NB 16384
#define KSTEPS 10
#define LDA 1152           // bytes/row: 1024 state + 64 X + 1 const + 63 pad
#define KD 1088            // GEMM K-dim: 1024 state + 64 X (cst in epilogue)
#define NT 17              // KD/64 K-iterations (compile-time, fully unrolled)
#define SLS 136            // epilogue slab row stride in bytes (128 + 8 pad)
#define USALT 4000u
#define BONE ((unsigned char)7)     // binary-one storage value (i8)
#define PSC 0x1.0p-13f              // common int->value scale p
#define RWQ 1170.2857142857f        // 8192/7: W & cst quantizer
#define SGQ 64.0f                   // G quantizer
#define SXQ 128.0f                  // X quantizer

typedef __attribute__((ext_vector_type(4))) float f32x4;
typedef __attribute__((ext_vector_type(4))) int i32x4;
typedef __attribute__((ext_vector_type(4))) unsigned int u32x4;

__device__ __forceinline__ unsigned hash32(unsigned idx, unsigned salt) {
  unsigned x = idx + salt * 0x9E3779B9u;
  x = (x ^ (x >> 16)) * 0x7feb352du;
  x = (x ^ (x >> 15)) * 0x846ca68bu;
  return x ^ (x >> 16);
}
__device__ __forceinline__ float rng_u01(unsigned salt, unsigned idx) {
  return (float)(hash32(idx, salt) >> 8) * (1.0f / 16777216.0f);
}
__device__ __forceinline__ float sigm(float z) { return 1.0f / (1.0f + __expf(-z)); }
// fast softplus: max(z,0) + log(1+exp(-|z|)); v_exp/v_log based.
__device__ __forceinline__ float softplus_(float z) {
  return fmaxf(z, 0.f) + __logf(1.f + __expf(-fabsf(z)));
}
__device__ __forceinline__ float lse2(float a, float b) {
  float m = fmaxf(a, b);
  return m + log1pf(__expf(fminf(a, b) - m));
}
// saturating i8 quantizer (returns bit pattern)
__device__ __forceinline__ unsigned char qi8(float v, float s) {
  float x = rintf(v * s);
  x = fminf(fmaxf(x, -127.f), 127.f);
  return (unsigned char)(signed char)(int)x;
}
__device__ __forceinline__ void gl2lds16(const void* g, void* l) {
  __builtin_amdgcn_global_load_lds(
      (const __attribute__((address_space(1))) unsigned int*)g,
      (__attribute__((address_space(3))) unsigned int*)l, 16, 0, 0);
}

// ---------------------------------------------------------------------------
// C = A[16384 x KD] *i8* Bt[. x KD]^T (epilogue: z = acc*PSC + cst),
// mfma_i32_16x16x64_i8, BK=64 (ONE K-slice/iter), NT=17 fully unrolled,
// double-buffered LDS, ONE barrier/iter.
// Chain (EPI0/1): BM=128 tile, 4 waves x 64x64, grid 1024:
//   xcd=L&7, li=L>>3; m0 = xcd*2048 + (li&15)*128; n-tile = li>>4.
// EPI2: BM=64 tile, 4 waves x 32x64, grid 2304 (incl. bias n-tile 8):
//   m0 = xcd*2048 + (li&31)*64; n-tile = li>>5.
// EPI 0: h = bern(sigm(z1)) -> sh. EPI 1: u_t inline; p0+=sum z, p1+=sum v*z
// (v via LDS-staged old-S tile); s_new -> sh. EPI 2: split-acc (acc it<16 =
// vW; accf it==16 = X.Gc); n<8 softplus rows; n==8 bias-dots.
// ---------------------------------------------------------------------------
template <int EPI>
__global__ __launch_bounds__(256, 4) void gemm_bt(
    const unsigned char* __restrict__ A, const unsigned char* __restrict__ Bt,
    unsigned char* sh, const float* __restrict__ cst,
    const float* __restrict__ wcs, const float* __restrict__ Xf,
    const float* __restrict__ pv0, const float* __restrict__ pv1, unsigned usalt,
    float* __restrict__ p0, float* __restrict__ p1, float* __restrict__ p2,
    unsigned salt) {
  constexpr int MI = (EPI == 2 ? 2 : 4);   // 16-row tiles per wave (M dir)
  constexpr int BM = MI * 32;              // block rows: 64 (EPI2) / 128
  constexpr int ABYT = BM * 64;            // A-panel bytes/buffer: 4K / 8K
  constexpr int BUF = ABYT + 8192;         // buffer stride: 12K / 16K
  // epilogue slab BM x 136 B aliases the front after the loop (chain only);
  // EPI1 stages the old-S tile (BM x 128 B) into the buffer-1 region.
  __shared__ __align__(16) char smem[2 * BUF];
  unsigned char* newsl = (unsigned char*)smem;

  const int t = threadIdx.x;
  const int L = blockIdx.x;
  const int xcd = L & 7, li = L >> 3;
  constexpr int MMSK = (EPI == 2 ? 31 : 15);
  constexpr int NSH = (EPI == 2 ? 5 : 4);
  const int m0 = xcd * 2048 + (li & MMSK) * BM;
  const int n0 = (li >> NSH) * 128;
  const int lane = t & 63, wave = t >> 6;
  const int wm = (wave >> 1) * (MI * 16), wn = (wave & 1) * 64;
  const int lr = lane & 15, quad = lane >> 4;
  // staging: lane -> row = lane>>2, phys chunk lane&3; gathers LOGICAL chunk
  // q = (lane&3) ^ (row&3) ^ ((lane>>4)&3)   [double-XOR swizzle]
  const int row8 = lane >> 2;
  const int qch = (((lane & 3) ^ (row8 & 3) ^ ((lane >> 4) & 3)) << 4);
  // i8 K=64 fragment: lane holds k = quad*16..+16 -> logical chunk = quad;
  // phys chunk = quad ^ rx(row), one b128 read.
  const int rx = (lr & 3) ^ ((lr >> 2) & 3);
  const int kph = ((quad ^ rx) << 4);

  // staging base pointers; per-iter advance folds to immediates (unrolled)
  const unsigned char* gA0 = A + (size_t)(m0 + wave * (MI * 8) + row8) * LDA + qch;
  const unsigned char* gA1 = gA0 + (size_t)16 * LDA;  // chain only
  const unsigned char* gB0 = Bt + (size_t)(n0 + wave * 32 + row8) * LDA + qch;
  const unsigned char* gB1 = gB0 + (size_t)16 * LDA;

  auto stage = [&](int it, int bufb) {
    const int ko = it * 64;
    if constexpr (EPI == 2) {
      gl2lds16(gA0 + ko, smem + bufb + wave * 1024);
    } else {
      gl2lds16(gA0 + ko, smem + bufb + wave * 2048);
      gl2lds16(gA1 + ko, smem + bufb + wave * 2048 + 1024);
    }
    gl2lds16(gB0 + ko, smem + bufb + ABYT + wave * 2048);
    gl2lds16(gB1 + ko, smem + bufb + ABYT + wave * 2048 + 1024);
  };

  i32x4 acc[MI][4] = {};
  i32x4 accf[EPI == 2 ? MI : 1][4] = {};  // EPI2 only: FiLM iter = X.Gc

  // prologue: stage K-tile 0 into buffer 0
  stage(0, 0);
  __syncthreads();

#pragma unroll
  for (int it = 0; it < NT; ++it) {
    const int base = (it & 1) * BUF;          // compile-time per body
    if (it + 1 < NT) stage(it + 1, base ^ BUF);
    const char* sA = (const char*)smem + base;
    const char* sB = sA + ABYT;
    i32x4 af[MI], bfr[4];
#pragma unroll
    for (int i = 0; i < MI; i++)
      af[i] = *(const i32x4*)(sA + (wm + i * 16 + lr) * 64 + kph);
#pragma unroll
    for (int j = 0; j < 4; j++)
      bfr[j] = *(const i32x4*)(sB + (wn + j * 16 + lr) * 64 + kph);
    if (EPI == 2 && it >= 16) {  // FiLM iter (k 1024..1087) -> accf
#pragma unroll
      for (int i = 0; i < MI; i++)
#pragma unroll
        for (int j = 0; j < 4; j++)
          accf[i][j] = __builtin_amdgcn_mfma_i32_16x16x64_i8(af[i], bfr[j], accf[i][j], 0, 0, 0);
    } else {
#pragma unroll
      for (int i = 0; i < MI; i++)
#pragma unroll
        for (int j = 0; j < 4; j++)
          acc[i][j] = __builtin_amdgcn_mfma_i32_16x16x64_i8(af[i], bfr[j], acc[i][j], 0, 0, 0);
    }
    // ONE barrier per iter: its vmcnt(0) drain covers the prefetch (in
    // flight across the whole compute phase) and orders reads-of-base
    // before the next overwrite.
    __syncthreads();
  }

  // per-thread cst values for this thread's 4 column slots (L1-resident)
  float cst_j[4];
  if constexpr (EPI != 2) {
#pragma unroll
    for (int j = 0; j < 4; j++) cst_j[j] = cst[n0 + wn + j * 16 + lr];
  }

  // C/D layout (m89, dtype-independent): col = lane&15, row = quad*4 + reg
  if constexpr (EPI == 2) {
    if (n0 >= 1024) {  // bias-dot tile: cols 1024..1088 = [Gb-dots | cstb]
#pragma unroll
      for (int i = 0; i < MI; i++)
#pragma unroll
        for (int rg = 0; rg < 4; rg++) {
          const int r = m0 + wm + i * 16 + quad * 4 + rg;
          float pb = 0.f;
          if (wn == 0) {  // cg = j*16+lr in 0..63: G-dots with X[r]
#pragma unroll
            for (int j = 0; j < 4; j++)
              pb += (float)acc[i][j][rg] * Xf[(size_t)r * 64 + j * 16 + lr];
            pb *= (1.f / 448.f);            // /(7 * SGQ)
          } else {        // col 1088 (j==0,lr==0): cst-dot
            if (lr == 0) pb = (float)acc[i][0][rg] * PSC;
          }
#pragma unroll
          for (int msk = 1; msk < 16; msk <<= 1) pb += __shfl_xor(pb, msk, 64);
          if (lr == 0) atomicAdd(&p2[r], pb);
        }
      return;
    }
    float cstc_j[4];
#pragma unroll
    for (int j = 0; j < 4; j++) cstc_j[j] = cst[n0 + wn + j * 16 + lr];
#pragma unroll
    for (int i = 0; i < MI; i++)
#pragma unroll
      for (int rg = 0; rg < 4; rg++) {
        const int r = m0 + wm + i * 16 + quad * 4 + rg;
        bool uu = true;
        if (pv0 != nullptr) {
          const float dE = -pv0[r] + 2.f * pv1[r];
          uu = rng_u01(usalt, (unsigned)r) < sigm(dE);
        }
        float sn = 0.f, sf = 0.f;
#pragma unroll
        for (int j = 0; j < 4; j++) {
          const int n = n0 + wn + j * 16 + lr;
          const float vw = (float)acc[i][j][rg] * PSC;
          const float cm = (float)accf[i][j][rg] * PSC + cstc_j[j];
          const float s1 = softplus_(vw + cm);
          const float s2 = softplus_(wcs[n] - vw + cm);
          sn += uu ? s1 : s2;
          sf += uu ? s2 : s1;
        }
#pragma unroll
        for (int msk = 1; msk < 16; msk <<= 1) {
          sn += __shfl_xor(sn, msk, 64);
          sf += __shfl_xor(sf, msk, 64);
        }
        if (lr == 0) { atomicAdd(&p0[r], sn); atomicAdd(&p1[r], sf); }
      }
    return;
  }

  if constexpr (EPI == 1) {  // z-sums with v from OLD s; u_t inline
    // Stage this block's OLD-S tile (BM x 128 B) into the buffer-1 region
    // (dead after the loop: last tile computed in buffer 0 since NT odd).
    // m173: linear LDS dest + PRE-SWIZZLED global source, so lds chunk c of
    // row r holds global chunk c ^ ((r>>2)&3).
    {
      const int rb = wave * (MI * 8);            // 32 rows per wave (BM=128)
#pragma unroll
      for (int q = 0; q < MI; ++q) {
        const int row = rb + q * 8 + (lane >> 3);
        const int sc = (lane & 7) ^ ((row >> 2) & 3);
        gl2lds16(sh + (size_t)(m0 + row) * LDA + n0 + sc * 16,
                 (unsigned char*)smem + BUF + (rb + q * 8) * 128);
      }
    }
    __syncthreads();  // drains vmcnt -> old-S tile published in LDS
    const unsigned char* osl = (const unsigned char*)smem + BUF;
#pragma unroll
    for (int i = 0; i < MI; i++)
#pragma unroll
      for (int rg = 0; rg < 4; rg++) {
        const int r = m0 + wm + i * 16 + quad * 4 + rg;
        const int rowl = wm + i * 16 + quad * 4 + rg;
        const float dE = -pv0[r] + 2.f * pv1[r];
        const bool uu = rng_u01(usalt, (unsigned)r) < sigm(dE);
        float q0 = 0.f, q1 = 0.f;
#pragma unroll
        for (int j = 0; j < 4; ++j) {
          const float z = (float)acc[i][j][rg] * PSC + cst_j[j];
          // read-side swizzle: (rowl>>2)&3 == quad for our row decomposition
          const int pc = ((wn >> 4) + j) ^ quad;
          const float so = (osl[rowl * 128 + pc * 16 + lr] != 0) ? 1.f : 0.f;
          const float v = uu ? so : 1.f - so;
          q0 += z; q1 += v * z;
        }
#pragma unroll
        for (int msk = 1; msk < 16; msk <<= 1) {
          q0 += __shfl_xor(q0, msk, 64);
          q1 += __shfl_xor(q1, msk, 64);
        }
        if (lr == 0) { atomicAdd(&p0[r], q0); atomicAdd(&p1[r], q1); }
      }
    __syncthreads();  // all old-S reads done before slab overwrites [BUF,..)
  }

  // EPI 0/1: sample into BM-row slab, 1 barrier, coalesced store
#pragma unroll
  for (int i = 0; i < MI; ++i)
#pragma unroll
    for (int rg = 0; rg < 4; ++rg) {
      const int rowl = wm + i * 16 + quad * 4 + rg;  // 0..BM-1 in tile
      const int r = m0 + rowl;
#pragma unroll
      for (int jp = 0; jp < 2; ++jp) {
        const unsigned x = hash32((unsigned)(r << 10) + (unsigned)(n0 + wn + jp * 16 + lr), salt);
        const float f0 = (float)(x & 0xFFFFu), f1 = (float)(x >> 16);
        const float z0 = (float)acc[i][jp][rg] * PSC + cst_j[jp];
        const float z1v = (float)acc[i][jp + 2][rg] * PSC + cst_j[jp + 2];
        newsl[rowl * SLS + wn + jp * 16 + lr] =
            (f0 * __expf(-z0) < 65536.f - f0) ? BONE : (unsigned char)0;
        newsl[rowl * SLS + wn + (jp + 2) * 16 + lr] =
            (f1 * __expf(-z1v) < 65536.f - f1) ? BONE : (unsigned char)0;
      }
    }
  __syncthreads();
#pragma unroll
  for (int p = 0; p < BM / 32; ++p) {  // BM rows x 128 B, fully coalesced
    const int c = p * 256 + t, rowl = c >> 3, chk = c & 7;
    const u32x4 vv = *(const u32x4*)(newsl + rowl * SLS + chk * 16);
    *(u32x4*)(sh + (size_t)(m0 + rowl) * LDA + n0 + chk * 16) = vv;
  }
}

// ------------------------- setup / small kernels ---------------------------
__global__ __launch_bounds__(256) void k_x(const float* __restrict__ cond,
                                           const float* __restrict__ fc1w,
                                           const float* __restrict__ fc1b, float* __restrict__ X) {
  int idx = blockIdx.x * 256 + threadIdx.x;
  int r = idx >> 6, k = idx & 63;
  X[idx] = tanhf(cond[r] * fc1w[k] + fc1b[k]);
}

__global__ __launch_bounds__(256) void k_g(const float* __restrict__ fc2w,
                                           const float* __restrict__ fc2b,
                                           const float* __restrict__ b, const float* __restrict__ c,
                                           float* __restrict__ Gb, float* __restrict__ Gc,
                                           float* __restrict__ cstb, float* __restrict__ cstc) {
  int idx = blockIdx.x * 256 + threadIdx.x;
  int j = idx >> 6, k = idx & 63;
  Gb[idx] = fc2w[(size_t)j * 64 + k] * b[j] + fc2w[(size_t)(1024 + j) * 64 + k];
  Gc[idx] = fc2w[(size_t)(2048 + j) * 64 + k] * c[j] + fc2w[(size_t)(3072 + j) * 64 + k];
  if (k == 0) {
    cstb[j] = b[j] + fc2b[j] * b[j] + fc2b[1024 + j];
    cstc[j] = c[j] + fc2b[2048 + j] * c[j] + fc2b[3072 + j];
  }
}

// i8 pack. Wt rows n<1024: [W^T(RWQ)|Gc(SGQ)|cst|pad]; rows 1024..1087:
// Gb-col profiles (SGQ); row 1088: cstb (RWQ). Wb mirror with W/Gb/cstb.
// Rows >=1024 are zero at k>=1024 -> EPI2 bias-tile accf==0.
__global__ __launch_bounds__(256) void k_prep(const float* __restrict__ W,
                                              const float* __restrict__ Gb,
                                              const float* __restrict__ Gc,
                                              const float* __restrict__ cstb,
                                              const float* __restrict__ cstc,
                                              unsigned char* __restrict__ Wt,
                                              unsigned char* __restrict__ Wb) {
  int k = blockIdx.x * 256 + threadIdx.x;
  int n = blockIdx.y;
  if (k >= LDA) return;
  unsigned char wt = 0, wb = 0;
  if (n < 1024) {
    if (k < 1024) {
      wt = qi8(W[(size_t)k * 1024 + n], RWQ);
      wb = qi8(W[(size_t)n * 1024 + k], RWQ);
    } else if (k < 1088) {
      int j = k - 1024;
      wt = qi8(Gc[(size_t)n * 64 + j], SGQ);
      wb = qi8(Gb[(size_t)n * 64 + j], SGQ);
    } else if (k == 1088) {  // unused at KD=1088
      wt = qi8(cstc[n], RWQ);
      wb = qi8(cstb[n], RWQ);
    }
  } else if (k < 1024) {
    if (n < 1088) wt = qi8(Gb[(size_t)k * 64 + (n - 1024)], SGQ);
    else if (n == 1088) wt = qi8(cstb[k], RWQ);
  }
  Wt[(size_t)n * LDA + k] = wt;
  Wb[(size_t)n * LDA + k] = wb;
}

__global__ __launch_bounds__(256) void k_wcs(const float* __restrict__ W, float* __restrict__ wcs) {
  int n = blockIdx.x * 256 + threadIdx.x;
  float s = 0.f;
  for (int i = 0; i < 1024; i++) s += W[(size_t)i * 1024 + n];
  wcs[n] = s;
}

// aux[k<64] = sum_j Gb[j][k]; aux[64] = sum_j cstb[j]
__global__ __launch_bounds__(128) void k_aux(const float* __restrict__ Gb,
                                             const float* __restrict__ cstb,
                                             float* __restrict__ aux) {
  int t = threadIdx.x;
  if (t < 64) {
    float s = 0.f;
    for (int j = 0; j < 1024; j++) s += Gb[(size_t)j * 64 + t];
    aux[t] = s;
  } else if (t == 64) {
    float s = 0.f;
    for (int j = 0; j < 1024; j++) s += cstb[j];
    aux[64] = s;
  }
}

__global__ __launch_bounds__(256) void k_sinit(const float* __restrict__ vdata,
                                               const float* __restrict__ X,
                                               unsigned char* __restrict__ S,
                                               unsigned char* __restrict__ H,
                                               unsigned char* __restrict__ V) {
  int k = blockIdx.x * 256 + threadIdx.x;
  int r = blockIdx.y;
  if (k >= LDA) return;
  const size_t o = (size_t)r * LDA + k;
  if (k < 1024) {
    float vd = vdata[(size_t)r * 1024 + k];
    V[o] = (vd != 0.f) ? BONE : (unsigned char)0;
    const bool u0 = rng_u01(USALT, (unsigned)r) < 0.5f;  // == EPI1 step-0 formula
    float sv = u0 ? vd : 1.f - vd;
    S[o] = (sv != 0.f) ? BONE : (unsigned char)0;
  } else {
    unsigned char xv = 0;
    if (k < 1088) xv = qi8(X[(size_t)r * 64 + (k - 1024)], SXQ);
    S[o] = xv; H[o] = xv; V[o] = xv;  // FiLM cols for K>=1024 GEMM iters
  }
}

// per-row scalar finale: sb from rank-64 closed form, d1/d2 from bias-dots
__global__ __launch_bounds__(256) void k_final(
    const float* __restrict__ Xf, const float* __restrict__ aux,
    const float* __restrict__ pv0, const float* __restrict__ pv1, unsigned usalt,
    const float* __restrict__ spn_d, const float* __restrict__ spf_d,
    const float* __restrict__ spn_m, const float* __restrict__ spf_m,
    const float* __restrict__ vb_d, const float* __restrict__ vb_m,
    float* __restrict__ fdiff) {
  __shared__ float ax[65];
  int t = threadIdx.x;
  if (t < 65) ax[t] = aux[t];
  __syncthreads();
  int r = blockIdx.x * 256 + t;
  float sb = ax[64];
  const float* xr = Xf + (size_t)r * 64;
#pragma unroll
  for (int k = 0; k < 64; k++) sb += xr[k] * ax[k];
  const float dE = -pv0[r] + 2.f * pv1[r];
  const bool uu = rng_u01(usalt, (unsigned)r) < sigm(dE);
  const float d1 = vb_d[r], d2 = vb_m[r];
  float F_d = -lse2(d1 + spn_d[r], (sb - d1) + spf_d[r]);
  float vbn = uu ? d2 : (sb - d2);
  float F_m = -lse2(vbn + spn_m[r], (sb - vbn) + spf_m[r]);
  fdiff[r] = F_d - F_m;
}

__global__ __launch_bounds__(256) void k_reduce(const float* __restrict__ fdiff,
                                                float* __restrict__ out) {
  __shared__ float red[4];
  int t = threadIdx.x;
  float s = 0.f;
  for (int i = t; i < NB; i += 256) s += fdiff[i];
  for (int m = 32; m >= 1; m >>= 1) s += __shfl_xor(s, m, 64);
  if ((t & 63) == 0) red[t >> 6] = s;
  __syncthreads();
  if (t == 0) out[0] = (red[0] + red[1] + red[2] + red[3]) * (1.0f / (float)NB);
}

// ---------------------------------------------------------------------------
extern "C" void kernel_launch(void* const* d_in, const int* in_sizes, int n_in, void* d_out,
                              int out_size, void* d_ws, size_t ws_size, hipStream_t stream) {
  const float* vdata = (const float*)d_in[0];
  const float* cond = (const float*)d_in[1];
  const float* W = (const float*)d_in[2];
  const float* bb = (const float*)d_in[3];
  const float* cc = (const float*)d_in[4];
  const float* fc1w = (const float*)d_in[5];
  const float* fc1b = (const float*)d_in[6];
  const float* fc2w = (const float*)d_in[7];
  const float* fc2b = (const float*)d_in[8];
  float* out = (float*)d_out;

  char* wp = (char*)d_ws;
  auto alloc = [&](size_t bytes) {
    char* p = wp;
    wp += (bytes + 255) & ~(size_t)255;
    return p;
  };
  unsigned char* Wt = (unsigned char*)alloc((size_t)1152 * LDA);
  unsigned char* Wb = (unsigned char*)alloc((size_t)1152 * LDA);
  float* wcs = (float*)alloc(1024 * 4);
  float* X = (float*)alloc((size_t)NB * 64 * 4);
  float* Gb = (float*)alloc((size_t)1024 * 64 * 4);
  float* Gc = (float*)alloc((size_t)1024 * 64 * 4);
  float* cstb = (float*)alloc(1024 * 4);
  float* cstc = (float*)alloc(1024 * 4);
  float* aux = (float*)alloc(65 * 4);
  unsigned char* S = (unsigned char*)alloc((size_t)NB * LDA);
  unsigned char* H = (unsigned char*)alloc((size_t)NB * LDA);
  unsigned char* V = (unsigned char*)alloc((size_t)NB * LDA);
  // per-step dE accumulators: pair t at pall + (t+1)*2*NB, t=-1..9; then 6 arrays
  float* pall = (float*)alloc((size_t)(KSTEPS + 1 + 3) * 2 * NB * 4);
  float* spn_d = pall + (size_t)(KSTEPS + 1) * 2 * NB;
  float* spf_d = spn_d + NB;
  float* spn_m = spf_d + NB;
  float* spf_m = spn_m + NB;
  float* vb_d = spf_m + NB;
  float* vb_m = vb_d + NB;
  float* fdiff = (float*)alloc(NB * 4);
  auto P0 = [&](int t) { return pall + (size_t)(t + 1) * 2 * NB; };
  auto P1 = [&](int t) { return pall + (size_t)(t + 1) * 2 * NB + NB; };

  hipMemsetAsync(pall, 0, (size_t)(KSTEPS + 1 + 3) * 2 * NB * 4, stream);

  k_x<<<NB * 64 / 256, 256, 0, stream>>>(cond, fc1w, fc1b, X);
  k_g<<<1024 * 64 / 256, 256, 0, stream>>>(fc2w, fc2b, bb, cc, Gb, Gc, cstb, cstc);
  k_prep<<<dim3(5, 1152), 256, 0, stream>>>(W, Gb, Gc, cstb, cstc, Wt, Wb);
  k_wcs<<<4, 256, 0, stream>>>(W, wcs);
  k_aux<<<1, 128, 0, stream>>>(Gb, cstb, aux);
  k_sinit<<<dim3(5, NB), 256, 0, stream>>>(vdata, X, S, H, V);

  for (int step = 0; step < KSTEPS; ++step) {
    // z1 = sW + c_mod (ext-K, +cstc epi); h ~ Bern(sigm(z1)) -> H
    gemm_bt<0><<<1024, 256, 0, stream>>>(S, Wt, H, cstc, nullptr, nullptr,
                                         nullptr, nullptr, 0u, nullptr, nullptr, nullptr,
                                         2000u + (unsigned)step);
    // z2 = hW^T + b_mod (ext-K, +cstb epi); u_t inline; dE partials; s_new -> S
    gemm_bt<1><<<1024, 256, 0, stream>>>(H, Wb, S, cstb, nullptr, nullptr,
                                         P0(step - 1), P1(step - 1), USALT + (unsigned)step,
                                         P0(step), P1(step), nullptr,
                                         3000u + (unsigned)step);
  }

  // Free-energy: softplus rows (n-tiles 0..7, split-acc; cm = accf*P+cstc) +
  // bias-dots (n-tile 8). i8 path (R21); cst in epilogue (R19).
  gemm_bt<2><<<2304, 256, 0, stream>>>(V, Wt, nullptr, cstc, wcs, X, nullptr, nullptr, 0u,
                                       spn_d, spf_d, vb_d, 0u);
  gemm_bt<2><<<2304, 256, 0, stream>>>(S, Wt, nullptr, cstc, wcs, X,
                                       P0(KSTEPS - 1), P1(KSTEPS - 1), USALT + KSTEPS,
                                       spn_m, spf_m, vb_m, 0u);
  k_final<<<NB / 256, 256, 0, stream>>>(X, aux, P0(KSTEPS - 1), P1(KSTEPS - 1), USALT + KSTEPS,
                                        spn_d, spf_d, spn_m, spf_m, vb_d, vb_m, fdiff);
  k_reduce<<<1, 256, 0, stream>>>(fdiff, out);
}